// Round 16
// baseline (754.406 us; speedup 1.0000x reference)
//
#include <hip/hip_runtime.h>

// GraphSAGE 3-layer (mean agg), N=100000, E=1600000, 128->32->32->16.
// Round 16 = round 15 + proj restructure:
//  - blockIdx.y selects self/neigh half -> LDS per block halves (16.5KB) ->
//    8 blocks/CU (was 4-cap), grid doubles -> no resident-tail starvation.
//  - x float4 loads explicitly double-buffered (issue k4+1 before k4's FMAs)
//    to cover global-load latency (proj1 pinned at ~41us, VALUBusy 35%,
//    0 conflicts across 4 formulations -> latency + occupancy were left).
// CSR build + feature-parallel gather unchanged from round 15.

#define BLOCK 256
#define NBLK 256            // blocks for hist/part passes
#define BSH 9               // 512 nodes per bucket
#define CAP 12288           // max edges per bucket staged in LDS

// ---------------- phase 1: per-(bucket,block) histogram of dst ----------------
__global__ void hist_kernel(const int* __restrict__ dst, int* __restrict__ hist,
                            int n_edges, int nbuk, int ch) {
    __shared__ int cnt[256];
    int tid = threadIdx.x;
    for (int i = tid; i < nbuk; i += BLOCK) cnt[i] = 0;
    __syncthreads();
    int e0 = blockIdx.x * ch;
    int e1 = e0 + ch; if (e1 > n_edges) e1 = n_edges;
    for (int e = e0 + tid; e < e1; e += BLOCK)
        atomicAdd(&cnt[dst[e] >> BSH], 1);
    __syncthreads();
    for (int i = tid; i < nbuk; i += BLOCK)
        hist[i * NBLK + blockIdx.x] = cnt[i];
}

// ---------------- phase 2a: per-bucket exclusive scan of its 256 block-counts ----------------
__global__ void scanBlk_kernel(int* __restrict__ hist, int* __restrict__ buktot) {
    int b = blockIdx.x;
    int tid = threadIdx.x;
    int orig = hist[b * NBLK + tid];
    int v = orig;
    int lane = tid & 63, w = tid >> 6;
#pragma unroll
    for (int off = 1; off < 64; off <<= 1) {
        int u = __shfl_up(v, off);
        if (lane >= off) v += u;
    }
    __shared__ int wps[4];
    if (lane == 63) wps[w] = v;
    __syncthreads();
    int wadd = 0;
    for (int k = 0; k < w; ++k) wadd += wps[k];
    int excl = v - orig + wadd;
    hist[b * NBLK + tid] = excl;
    if (tid == 255) buktot[b] = excl + orig;
}

// ---------------- phase 2b: exclusive scan of bucket totals (1 block) ----------------
__global__ void scanBuk_kernel(const int* __restrict__ buktot, int* __restrict__ bukoff,
                               int nbuk, int* __restrict__ startp, int n_nodes, int n_edges) {
    int tid = threadIdx.x;
    int orig = (tid < nbuk) ? buktot[tid] : 0;
    int v = orig;
    int lane = tid & 63, w = tid >> 6;
#pragma unroll
    for (int off = 1; off < 64; off <<= 1) {
        int u = __shfl_up(v, off);
        if (lane >= off) v += u;
    }
    __shared__ int wps[4];
    if (lane == 63) wps[w] = v;
    __syncthreads();
    int wadd = 0;
    for (int k = 0; k < w; ++k) wadd += wps[k];
    int excl = v - orig + wadd;
    if (tid < nbuk) bukoff[tid] = excl;
    if (tid == 0) { bukoff[nbuk] = n_edges; startp[n_nodes] = n_edges; }
}

// ---------------- phase 3: partition packed (src|dl<<20) bucket-contiguously ----------------
__global__ void part_kernel(const int* __restrict__ src, const int* __restrict__ dst,
                            const int* __restrict__ hist, const int* __restrict__ bukoff,
                            unsigned* __restrict__ pairs, int n_edges, int nbuk, int ch) {
    __shared__ int base[256];
    __shared__ int cnt[256];
    int tid = threadIdx.x;
    for (int i = tid; i < nbuk; i += BLOCK) {
        base[i] = hist[i * NBLK + blockIdx.x] + bukoff[i];
        cnt[i] = 0;
    }
    __syncthreads();
    int e0 = blockIdx.x * ch;
    int e1 = e0 + ch; if (e1 > n_edges) e1 = n_edges;
    for (int e = e0 + tid; e < e1; e += BLOCK) {
        int d = dst[e];
        int b = d >> BSH;
        unsigned dl = (unsigned)(d & ((1 << BSH) - 1));
        int r = atomicAdd(&cnt[b], 1);
        pairs[base[b] + r] = (unsigned)src[e] | (dl << 20);
    }
}

// ---------------- phase 4: per-bucket CSR build in LDS ----------------
__global__ void build_kernel(const unsigned* __restrict__ pairs, const int* __restrict__ bukoff,
                             int* __restrict__ start, float* __restrict__ invdeg,
                             int* __restrict__ csr_src, int n_nodes) {
    __shared__ int deg[512];
    __shared__ int lst[512];
    __shared__ int cur[512];
    __shared__ int wps[4];
    __shared__ int scsr[CAP];

    int b = blockIdx.x;
    int tid = threadIdx.x;
    int e0 = bukoff[b];
    int e1 = bukoff[b + 1];
    int lo = b << BSH;
    int hi = lo + (1 << BSH); if (hi > n_nodes) hi = n_nodes;
    int nn = hi - lo;
    int ne = e1 - e0;

    for (int i = tid; i < 512; i += BLOCK) deg[i] = 0;
    __syncthreads();
    for (int i = e0 + tid; i < e1; i += BLOCK)
        atomicAdd(&deg[pairs[i] >> 20], 1);
    __syncthreads();

    int d0 = deg[2 * tid], d1 = deg[2 * tid + 1];
    int s = d0 + d1;
    int lane = tid & 63, w = tid >> 6;
    int v = s;
#pragma unroll
    for (int off = 1; off < 64; off <<= 1) {
        int u = __shfl_up(v, off);
        if (lane >= off) v += u;
    }
    if (lane == 63) wps[w] = v;
    __syncthreads();
    int wb = 0;
    for (int k = 0; k < w; ++k) wb += wps[k];
    int excl = wb + v - s;
    lst[2 * tid] = excl;
    lst[2 * tid + 1] = excl + d0;
    cur[2 * tid] = 0;
    cur[2 * tid + 1] = 0;
    __syncthreads();

    for (int i = tid; i < nn; i += BLOCK) {
        start[lo + i] = e0 + lst[i];
        int d = deg[i];
        invdeg[lo + i] = 1.0f / (float)(d < 1 ? 1 : d);
    }

    if (ne <= CAP) {
        for (int i = e0 + tid; i < e1; i += BLOCK) {
            unsigned pr = pairs[i];
            int dl = pr >> 20;
            int sl = lst[dl] + atomicAdd(&cur[dl], 1);
            scsr[sl] = (int)(pr & 0xFFFFFu);
        }
        __syncthreads();
        for (int i = tid; i < ne; i += BLOCK) csr_src[e0 + i] = scsr[i];
    } else {
        for (int i = e0 + tid; i < e1; i += BLOCK) {
            unsigned pr = pairs[i];
            int dl = pr >> 20;
            int sl = lst[dl] + atomicAdd(&cur[dl], 1);
            csr_src[e0 + sl] = (int)(pr & 0xFFFFFu);
        }
    }
}

// ---------------- projection (half-split): blockIdx.y==0 -> pre=h@Ws+b ; ==1 -> p=h@Wn ----------------
// One weight matrix per block staged in LDS (16KB @128x32). x float4 broadcast
// from global, explicitly double-buffered across k4 iterations.
template<int DIN, int DOUT, int OPT, int NPT>
__global__ __launch_bounds__(256, 8)
void proj_half(const float* __restrict__ h,
               const float* __restrict__ Ws,
               const float* __restrict__ Wn,
               const float* __restrict__ bias,
               float* __restrict__ pre,
               float* __restrict__ p,
               int n_nodes) {
    constexpr int OG  = DOUT / OPT;     // output groups (4 or 2)
    constexpr int NG  = 256 / OG;       // node groups (64 or 128)
    constexpr int NT  = NPT * NG;       // node tile (128 or 256)
    constexpr int NV  = OPT / 4;        // float4s of output per thread
    constexpr int K4  = DIN / 4;

    __shared__ float sW[DIN * DOUT];
    __shared__ float sb[DOUT];

    const bool self_half = (blockIdx.y == 0);
    const float* __restrict__ W = self_half ? Ws : Wn;

    const int tid = threadIdx.x;
    for (int i = tid; i < DIN * DOUT / 4; i += 256)
        *reinterpret_cast<float4*>(&sW[i * 4]) =
            *reinterpret_cast<const float4*>(W + (size_t)i * 4);
    if (tid < DOUT) sb[tid] = self_half ? bias[tid] : 0.f;
    __syncthreads();

    const int to = tid % OG;
    const int tn = tid / OG;
    const int o0 = to * OPT;
    const int node0 = blockIdx.x * NT + tn * NPT;

    const float4* __restrict__ xp[NPT];
#pragma unroll
    for (int n = 0; n < NPT; ++n) {
        int node = node0 + n;
        int safe = (node < n_nodes) ? node : (n_nodes - 1);
        xp[n] = reinterpret_cast<const float4*>(h + (size_t)safe * DIN);
    }

    float acc[NPT][OPT];
#pragma unroll
    for (int n = 0; n < NPT; ++n)
#pragma unroll
        for (int o = 0; o < OPT; ++o) acc[n][o] = 0.f;

    float4 xc[NPT];
#pragma unroll
    for (int n = 0; n < NPT; ++n) xc[n] = xp[n][0];

    for (int k4 = 0; k4 < K4; ++k4) {
        // issue next iteration's x loads early (latency covered by FMA block)
        float4 xn[NPT];
        int nk4 = (k4 + 1 < K4) ? (k4 + 1) : k4;
#pragma unroll
        for (int n = 0; n < NPT; ++n) xn[n] = xp[n][nk4];

#pragma unroll
        for (int kk = 0; kk < 4; ++kk) {
            int k = 4 * k4 + kk;
            float4 w[NV];
#pragma unroll
            for (int v = 0; v < NV; ++v)
                w[v] = *reinterpret_cast<const float4*>(&sW[k * DOUT + o0 + 4 * v]);
#pragma unroll
            for (int n = 0; n < NPT; ++n) {
                float xk = reinterpret_cast<const float*>(&xc[n])[kk];
#pragma unroll
                for (int v = 0; v < NV; ++v) {
                    acc[n][4 * v + 0] = fmaf(xk, w[v].x, acc[n][4 * v + 0]);
                    acc[n][4 * v + 1] = fmaf(xk, w[v].y, acc[n][4 * v + 1]);
                    acc[n][4 * v + 2] = fmaf(xk, w[v].z, acc[n][4 * v + 2]);
                    acc[n][4 * v + 3] = fmaf(xk, w[v].w, acc[n][4 * v + 3]);
                }
            }
        }
#pragma unroll
        for (int n = 0; n < NPT; ++n) xc[n] = xn[n];
    }

    float* __restrict__ dstbuf = self_half ? pre : p;
#pragma unroll
    for (int n = 0; n < NPT; ++n) {
        int node = node0 + n;
        if (node >= n_nodes) continue;
#pragma unroll
        for (int v = 0; v < NV; ++v) {
            float4 r;
            r.x = acc[n][4 * v + 0] + sb[o0 + 4 * v + 0];
            r.y = acc[n][4 * v + 1] + sb[o0 + 4 * v + 1];
            r.z = acc[n][4 * v + 2] + sb[o0 + 4 * v + 2];
            r.w = acc[n][4 * v + 3] + sb[o0 + 4 * v + 3];
            *reinterpret_cast<float4*>(dstbuf + (size_t)node * DOUT + o0 + 4 * v) = r;
        }
    }
}

// ---------------- feature-parallel gather + finalize (no reduce) ----------------
template<int D, bool RELU>
__global__ void gather_kernel(const float* __restrict__ p,
                              const int* __restrict__ csr_src,
                              const int* __restrict__ start,
                              const float* __restrict__ pre,
                              const float* __restrict__ invdeg,
                              float* __restrict__ out,
                              int n_nodes) {
    constexpr int NPW = 64 / D;         // nodes per wave (2 or 4)
    int wave = threadIdx.x >> 6;
    int lane = threadIdx.x & 63;
    int g = (blockIdx.x * (blockDim.x >> 6) + wave) * NPW + lane / D;
    int f = lane % D;
    if (g >= n_nodes) return;
    int s0 = start[g];
    int s1 = start[g + 1];
    float a0 = 0.f, a1 = 0.f, a2 = 0.f, a3 = 0.f;
    float a4 = 0.f, a5 = 0.f, a6 = 0.f, a7 = 0.f;
    int j = s0;
    for (; j + 8 <= s1; j += 8) {
        int c0 = csr_src[j + 0], c1 = csr_src[j + 1];
        int c2 = csr_src[j + 2], c3 = csr_src[j + 3];
        int c4 = csr_src[j + 4], c5 = csr_src[j + 5];
        int c6 = csr_src[j + 6], c7 = csr_src[j + 7];
        a0 += p[(size_t)c0 * D + f];
        a1 += p[(size_t)c1 * D + f];
        a2 += p[(size_t)c2 * D + f];
        a3 += p[(size_t)c3 * D + f];
        a4 += p[(size_t)c4 * D + f];
        a5 += p[(size_t)c5 * D + f];
        a6 += p[(size_t)c6 * D + f];
        a7 += p[(size_t)c7 * D + f];
    }
    for (; j + 2 <= s1; j += 2) {
        int c0 = csr_src[j], c1 = csr_src[j + 1];
        a0 += p[(size_t)c0 * D + f];
        a1 += p[(size_t)c1 * D + f];
    }
    if (j < s1) a2 += p[(size_t)csr_src[j] * D + f];
    float a = ((a0 + a1) + (a2 + a3)) + ((a4 + a5) + (a6 + a7));
    size_t o = (size_t)g * D + f;
    float v = pre[o] + a * invdeg[g];
    if (RELU) v = fmaxf(v, 0.f);
    out[o] = v;
}

extern "C" void kernel_launch(void* const* d_in, const int* in_sizes, int n_in,
                              void* d_out, int out_size, void* d_ws, size_t ws_size,
                              hipStream_t stream) {
    const float* x        = (const float*)d_in[0];
    const int*   edge_src = (const int*)d_in[1];
    const int*   edge_dst = (const int*)d_in[2];
    const float* Ws1 = (const float*)d_in[3];
    const float* Wn1 = (const float*)d_in[4];
    const float* b1  = (const float*)d_in[5];
    const float* Ws2 = (const float*)d_in[6];
    const float* Wn2 = (const float*)d_in[7];
    const float* b2  = (const float*)d_in[8];
    const float* Ws3 = (const float*)d_in[9];
    const float* Wn3 = (const float*)d_in[10];
    const float* b3  = (const float*)d_in[11];
    float* out = (float*)d_out;

    const int IN = 128, HID = 32;
    const int n_nodes = in_sizes[0] / IN;
    const int n_edges = in_sizes[1];
    const int nbuk = (n_nodes + (1 << BSH) - 1) >> BSH;   // 196
    const int ch   = (n_edges + NBLK - 1) / NBLK;         // 6250

    char* wsb = (char*)d_ws;
    size_t off = 0;
    auto alloc = [&](size_t bytes) { char* r = wsb + off; off = (off + bytes + 255) & ~(size_t)255; return r; };
    int*   startp = (int*)alloc(((size_t)n_nodes + 1) * sizeof(int));
    float* invdeg = (float*)alloc((size_t)n_nodes * sizeof(float));
    int*   csr    = (int*)alloc((size_t)n_edges * sizeof(int));
    int*   hist   = (int*)alloc((size_t)nbuk * NBLK * sizeof(int));
    int*   buktot = (int*)alloc(256 * sizeof(int));
    int*   bukoff = (int*)alloc(257 * sizeof(int));
    float* B0     = (float*)alloc((size_t)n_nodes * HID * sizeof(float));  // pre
    float* B1     = (float*)alloc((size_t)n_nodes * HID * sizeof(float));  // p
    float* B3     = (float*)alloc((size_t)n_nodes * HID * sizeof(float));  // h
    unsigned* pairs = (unsigned*)B0;   // CSR build fully precedes proj1 (6.4MB < B0)

    const int gP12   = (n_nodes + 127) / 128;    // proj L1/L2: NT=128
    const int gP3    = (n_nodes + 255) / 256;    // proj L3:    NT=256
    const int gGat32 = (n_nodes + 7) / 8;        // 8 nodes/block
    const int gGat16 = (n_nodes + 15) / 16;      // 16 nodes/block

    // ---- CSR build: hist -> hierarchical scan -> partition -> per-bucket build ----
    hist_kernel   <<<NBLK, BLOCK, 0, stream>>>(edge_dst, hist, n_edges, nbuk, ch);
    scanBlk_kernel<<<nbuk, BLOCK, 0, stream>>>(hist, buktot);
    scanBuk_kernel<<<1, BLOCK, 0, stream>>>(buktot, bukoff, nbuk, startp, n_nodes, n_edges);
    part_kernel   <<<NBLK, BLOCK, 0, stream>>>(edge_src, edge_dst, hist, bukoff, pairs, n_edges, nbuk, ch);
    build_kernel  <<<nbuk, BLOCK, 0, stream>>>(pairs, bukoff, startp, invdeg, csr, n_nodes);

    // ---- layer 1: 128 -> 32, relu ----
    proj_half<128, 32, 8, 2><<<dim3(gP12, 2), BLOCK, 0, stream>>>(x, Ws1, Wn1, b1, B0, B1, n_nodes);
    gather_kernel<32, true><<<gGat32, BLOCK, 0, stream>>>(B1, csr, startp, B0, invdeg, B3, n_nodes);

    // ---- layer 2: 32 -> 32, relu ----
    proj_half<32, 32, 8, 2><<<dim3(gP12, 2), BLOCK, 0, stream>>>(B3, Ws2, Wn2, b2, B0, B1, n_nodes);
    gather_kernel<32, true><<<gGat32, BLOCK, 0, stream>>>(B1, csr, startp, B0, invdeg, B3, n_nodes);

    // ---- layer 3: 32 -> 16, no relu ----
    proj_half<32, 16, 8, 2><<<dim3(gP3, 2), BLOCK, 0, stream>>>(B3, Ws3, Wn3, b3, B0, B1, n_nodes);
    gather_kernel<16, false><<<gGat16, BLOCK, 0, stream>>>(B1, csr, startp, B0, invdeg, out, n_nodes);
}

// Round 17
// 196.300 us; speedup vs baseline: 3.8431x; 3.8431x over previous
//
#include <hip/hip_runtime.h>

// GraphSAGE 3-layer (mean agg), N=100000, E=1600000, 128->32->32->16.
// Round 17 = round 15 (205us, best) + bf16 p-table for the gather phase.
// Round 16's half-split proj catastrophically over-fetched (538MB, 4-lane
// broadcast scatter + L1 thrash) -> full revert of proj to r15 form.
// bf16 here avoids r13's failure mode: feature-parallel gather has NO
// shuffle-reduce and unpacks 1 elem/load (r13's sub-group form unpacked 8 +
// 32 shuffles). p table 12.8->6.4MB, gather reads halve.

#define BLOCK 256
#define NBLK 256            // blocks for hist/part passes
#define BSH 9               // 512 nodes per bucket
#define CAP 12288           // max edges per bucket staged in LDS

__device__ __forceinline__ unsigned pack_bf16(float a, float b) {
    unsigned ua = __float_as_uint(a); ua = (ua + 0x7fffu + ((ua >> 16) & 1u)) >> 16;
    unsigned ub = __float_as_uint(b); ub = (ub + 0x7fffu + ((ub >> 16) & 1u)) >> 16;
    return ua | (ub << 16);
}

// ---------------- phase 1: per-(bucket,block) histogram of dst ----------------
__global__ void hist_kernel(const int* __restrict__ dst, int* __restrict__ hist,
                            int n_edges, int nbuk, int ch) {
    __shared__ int cnt[256];
    int tid = threadIdx.x;
    for (int i = tid; i < nbuk; i += BLOCK) cnt[i] = 0;
    __syncthreads();
    int e0 = blockIdx.x * ch;
    int e1 = e0 + ch; if (e1 > n_edges) e1 = n_edges;
    for (int e = e0 + tid; e < e1; e += BLOCK)
        atomicAdd(&cnt[dst[e] >> BSH], 1);
    __syncthreads();
    for (int i = tid; i < nbuk; i += BLOCK)
        hist[i * NBLK + blockIdx.x] = cnt[i];
}

// ---------------- phase 2a: per-bucket exclusive scan of its 256 block-counts ----------------
__global__ void scanBlk_kernel(int* __restrict__ hist, int* __restrict__ buktot) {
    int b = blockIdx.x;
    int tid = threadIdx.x;
    int orig = hist[b * NBLK + tid];
    int v = orig;
    int lane = tid & 63, w = tid >> 6;
#pragma unroll
    for (int off = 1; off < 64; off <<= 1) {
        int u = __shfl_up(v, off);
        if (lane >= off) v += u;
    }
    __shared__ int wps[4];
    if (lane == 63) wps[w] = v;
    __syncthreads();
    int wadd = 0;
    for (int k = 0; k < w; ++k) wadd += wps[k];
    int excl = v - orig + wadd;
    hist[b * NBLK + tid] = excl;
    if (tid == 255) buktot[b] = excl + orig;
}

// ---------------- phase 2b: exclusive scan of bucket totals (1 block) ----------------
__global__ void scanBuk_kernel(const int* __restrict__ buktot, int* __restrict__ bukoff,
                               int nbuk, int* __restrict__ startp, int n_nodes, int n_edges) {
    int tid = threadIdx.x;
    int orig = (tid < nbuk) ? buktot[tid] : 0;
    int v = orig;
    int lane = tid & 63, w = tid >> 6;
#pragma unroll
    for (int off = 1; off < 64; off <<= 1) {
        int u = __shfl_up(v, off);
        if (lane >= off) v += u;
    }
    __shared__ int wps[4];
    if (lane == 63) wps[w] = v;
    __syncthreads();
    int wadd = 0;
    for (int k = 0; k < w; ++k) wadd += wps[k];
    int excl = v - orig + wadd;
    if (tid < nbuk) bukoff[tid] = excl;
    if (tid == 0) { bukoff[nbuk] = n_edges; startp[n_nodes] = n_edges; }
}

// ---------------- phase 3: partition packed (src|dl<<20) bucket-contiguously ----------------
__global__ void part_kernel(const int* __restrict__ src, const int* __restrict__ dst,
                            const int* __restrict__ hist, const int* __restrict__ bukoff,
                            unsigned* __restrict__ pairs, int n_edges, int nbuk, int ch) {
    __shared__ int base[256];
    __shared__ int cnt[256];
    int tid = threadIdx.x;
    for (int i = tid; i < nbuk; i += BLOCK) {
        base[i] = hist[i * NBLK + blockIdx.x] + bukoff[i];
        cnt[i] = 0;
    }
    __syncthreads();
    int e0 = blockIdx.x * ch;
    int e1 = e0 + ch; if (e1 > n_edges) e1 = n_edges;
    for (int e = e0 + tid; e < e1; e += BLOCK) {
        int d = dst[e];
        int b = d >> BSH;
        unsigned dl = (unsigned)(d & ((1 << BSH) - 1));
        int r = atomicAdd(&cnt[b], 1);
        pairs[base[b] + r] = (unsigned)src[e] | (dl << 20);
    }
}

// ---------------- phase 4: per-bucket CSR build in LDS ----------------
__global__ void build_kernel(const unsigned* __restrict__ pairs, const int* __restrict__ bukoff,
                             int* __restrict__ start, float* __restrict__ invdeg,
                             int* __restrict__ csr_src, int n_nodes) {
    __shared__ int deg[512];
    __shared__ int lst[512];
    __shared__ int cur[512];
    __shared__ int wps[4];
    __shared__ int scsr[CAP];

    int b = blockIdx.x;
    int tid = threadIdx.x;
    int e0 = bukoff[b];
    int e1 = bukoff[b + 1];
    int lo = b << BSH;
    int hi = lo + (1 << BSH); if (hi > n_nodes) hi = n_nodes;
    int nn = hi - lo;
    int ne = e1 - e0;

    for (int i = tid; i < 512; i += BLOCK) deg[i] = 0;
    __syncthreads();
    for (int i = e0 + tid; i < e1; i += BLOCK)
        atomicAdd(&deg[pairs[i] >> 20], 1);
    __syncthreads();

    int d0 = deg[2 * tid], d1 = deg[2 * tid + 1];
    int s = d0 + d1;
    int lane = tid & 63, w = tid >> 6;
    int v = s;
#pragma unroll
    for (int off = 1; off < 64; off <<= 1) {
        int u = __shfl_up(v, off);
        if (lane >= off) v += u;
    }
    if (lane == 63) wps[w] = v;
    __syncthreads();
    int wb = 0;
    for (int k = 0; k < w; ++k) wb += wps[k];
    int excl = wb + v - s;
    lst[2 * tid] = excl;
    lst[2 * tid + 1] = excl + d0;
    cur[2 * tid] = 0;
    cur[2 * tid + 1] = 0;
    __syncthreads();

    for (int i = tid; i < nn; i += BLOCK) {
        start[lo + i] = e0 + lst[i];
        int d = deg[i];
        invdeg[lo + i] = 1.0f / (float)(d < 1 ? 1 : d);
    }

    if (ne <= CAP) {
        for (int i = e0 + tid; i < e1; i += BLOCK) {
            unsigned pr = pairs[i];
            int dl = pr >> 20;
            int sl = lst[dl] + atomicAdd(&cur[dl], 1);
            scsr[sl] = (int)(pr & 0xFFFFFu);
        }
        __syncthreads();
        for (int i = tid; i < ne; i += BLOCK) csr_src[e0 + i] = scsr[i];
    } else {
        for (int i = e0 + tid; i < e1; i += BLOCK) {
            unsigned pr = pairs[i];
            int dl = pr >> 20;
            int sl = lst[dl] + atomicAdd(&cur[dl], 1);
            csr_src[e0 + sl] = (int)(pr & 0xFFFFFu);
        }
    }
}

// ---------------- projection: pre = h@Ws + b (fp32) ; p = h@Wn (bf16) ----------------
// r15 body: W+bias staged in LDS once, x float4 broadcast, NPT=2/NT=64,
// k-unroll x2 (4 independent ds_read_b128 in flight). Neigh half packs bf16.
template<int DIN, int DOUT, int OPT, int NPT>
__global__ __launch_bounds__(256, 4)
void proj_reg(const float* __restrict__ h,
              const float* __restrict__ Ws,
              const float* __restrict__ Wn,
              const float* __restrict__ bias,
              float* __restrict__ pre,
              unsigned short* __restrict__ p,
              int n_nodes) {
    constexpr int OD  = 2 * DOUT;
    constexpr int OG  = OD / OPT;       // output groups
    constexpr int NG  = 256 / OG;       // node groups
    constexpr int NT  = NPT * NG;       // node tile (64)
    constexpr int NV  = OPT / 4;        // float4s of output per thread

    __shared__ float sW[DIN][OD];
    __shared__ float sb[DOUT];

    const int tid = threadIdx.x;
    for (int i = tid; i < DIN * OD; i += 256) {
        int k = i / OD, o = i % OD;
        sW[k][o] = (o < DOUT) ? Ws[k * DOUT + o] : Wn[k * DOUT + (o - DOUT)];
    }
    if (tid < DOUT) sb[tid] = bias[tid];
    __syncthreads();

    const int to = tid % OG;
    const int tn = tid / OG;
    const int o0 = to * OPT;
    const int node0 = blockIdx.x * NT + tn * NPT;

    const float4* __restrict__ xp[NPT];
#pragma unroll
    for (int n = 0; n < NPT; ++n) {
        int node = node0 + n;
        int safe = (node < n_nodes) ? node : (n_nodes - 1);
        xp[n] = reinterpret_cast<const float4*>(h + (size_t)safe * DIN);
    }

    float acc[NPT][OPT];
#pragma unroll
    for (int n = 0; n < NPT; ++n)
#pragma unroll
        for (int o = 0; o < OPT; ++o) acc[n][o] = 0.f;

#pragma unroll 2
    for (int k4 = 0; k4 < DIN / 4; ++k4) {
        float4 xv[NPT];
#pragma unroll
        for (int n = 0; n < NPT; ++n) xv[n] = xp[n][k4];
#pragma unroll
        for (int kk = 0; kk < 4; kk += 2) {
            int k = 4 * k4 + kk;
            float4 w0[NV], w1[NV];
#pragma unroll
            for (int v = 0; v < NV; ++v) {
                w0[v] = *reinterpret_cast<const float4*>(&sW[k][o0 + 4 * v]);
                w1[v] = *reinterpret_cast<const float4*>(&sW[k + 1][o0 + 4 * v]);
            }
#pragma unroll
            for (int n = 0; n < NPT; ++n) {
                float xk = reinterpret_cast<const float*>(&xv[n])[kk];
#pragma unroll
                for (int v = 0; v < NV; ++v) {
                    acc[n][4 * v + 0] = fmaf(xk, w0[v].x, acc[n][4 * v + 0]);
                    acc[n][4 * v + 1] = fmaf(xk, w0[v].y, acc[n][4 * v + 1]);
                    acc[n][4 * v + 2] = fmaf(xk, w0[v].z, acc[n][4 * v + 2]);
                    acc[n][4 * v + 3] = fmaf(xk, w0[v].w, acc[n][4 * v + 3]);
                }
            }
#pragma unroll
            for (int n = 0; n < NPT; ++n) {
                float xk = reinterpret_cast<const float*>(&xv[n])[kk + 1];
#pragma unroll
                for (int v = 0; v < NV; ++v) {
                    acc[n][4 * v + 0] = fmaf(xk, w1[v].x, acc[n][4 * v + 0]);
                    acc[n][4 * v + 1] = fmaf(xk, w1[v].y, acc[n][4 * v + 1]);
                    acc[n][4 * v + 2] = fmaf(xk, w1[v].z, acc[n][4 * v + 2]);
                    acc[n][4 * v + 3] = fmaf(xk, w1[v].w, acc[n][4 * v + 3]);
                }
            }
        }
    }

    const bool self_half = (o0 < DOUT);
    const int oo = self_half ? o0 : (o0 - DOUT);
#pragma unroll
    for (int n = 0; n < NPT; ++n) {
        int node = node0 + n;
        if (node >= n_nodes) continue;
        if (self_half) {
#pragma unroll
            for (int v = 0; v < NV; ++v) {
                float4 r;
                r.x = acc[n][4 * v + 0] + sb[oo + 4 * v + 0];
                r.y = acc[n][4 * v + 1] + sb[oo + 4 * v + 1];
                r.z = acc[n][4 * v + 2] + sb[oo + 4 * v + 2];
                r.w = acc[n][4 * v + 3] + sb[oo + 4 * v + 3];
                *reinterpret_cast<float4*>(pre + (size_t)node * DOUT + oo + 4 * v) = r;
            }
        } else {
            unsigned uw[OPT / 2];
#pragma unroll
            for (int v = 0; v < OPT / 2; ++v)
                uw[v] = pack_bf16(acc[n][2 * v], acc[n][2 * v + 1]);
            unsigned short* dstp = p + (size_t)node * DOUT + oo;
            if (OPT == 8) {
                *reinterpret_cast<uint4*>(dstp) = make_uint4(uw[0], uw[1], uw[2], uw[3]);
            } else {  // OPT == 4
                *reinterpret_cast<uint2*>(dstp) = make_uint2(uw[0], uw[1]);
            }
        }
    }
}

// ---------------- feature-parallel bf16 gather + finalize (no reduce) ----------------
// Lane owns one feature column; 64/D nodes per wave; 8 independent 2B row
// loads in flight (lanes of a row form one 64B segment); 1 cvt per load.
template<int D, bool RELU>
__global__ void gather_kernel(const unsigned short* __restrict__ p,
                              const int* __restrict__ csr_src,
                              const int* __restrict__ start,
                              const float* __restrict__ pre,
                              const float* __restrict__ invdeg,
                              float* __restrict__ out,
                              int n_nodes) {
    constexpr int NPW = 64 / D;         // nodes per wave (2 or 4)
    int wave = threadIdx.x >> 6;
    int lane = threadIdx.x & 63;
    int g = (blockIdx.x * (blockDim.x >> 6) + wave) * NPW + lane / D;
    int f = lane % D;
    if (g >= n_nodes) return;
    int s0 = start[g];
    int s1 = start[g + 1];
    float a0 = 0.f, a1 = 0.f, a2 = 0.f, a3 = 0.f;
    float a4 = 0.f, a5 = 0.f, a6 = 0.f, a7 = 0.f;
    int j = s0;
    for (; j + 8 <= s1; j += 8) {
        int c0 = csr_src[j + 0], c1 = csr_src[j + 1];
        int c2 = csr_src[j + 2], c3 = csr_src[j + 3];
        int c4 = csr_src[j + 4], c5 = csr_src[j + 5];
        int c6 = csr_src[j + 6], c7 = csr_src[j + 7];
        unsigned short u0 = p[(size_t)c0 * D + f];
        unsigned short u1 = p[(size_t)c1 * D + f];
        unsigned short u2 = p[(size_t)c2 * D + f];
        unsigned short u3 = p[(size_t)c3 * D + f];
        unsigned short u4 = p[(size_t)c4 * D + f];
        unsigned short u5 = p[(size_t)c5 * D + f];
        unsigned short u6 = p[(size_t)c6 * D + f];
        unsigned short u7 = p[(size_t)c7 * D + f];
        a0 += __uint_as_float((unsigned)u0 << 16);
        a1 += __uint_as_float((unsigned)u1 << 16);
        a2 += __uint_as_float((unsigned)u2 << 16);
        a3 += __uint_as_float((unsigned)u3 << 16);
        a4 += __uint_as_float((unsigned)u4 << 16);
        a5 += __uint_as_float((unsigned)u5 << 16);
        a6 += __uint_as_float((unsigned)u6 << 16);
        a7 += __uint_as_float((unsigned)u7 << 16);
    }
    for (; j + 2 <= s1; j += 2) {
        int c0 = csr_src[j], c1 = csr_src[j + 1];
        a0 += __uint_as_float((unsigned)p[(size_t)c0 * D + f] << 16);
        a1 += __uint_as_float((unsigned)p[(size_t)c1 * D + f] << 16);
    }
    if (j < s1)
        a2 += __uint_as_float((unsigned)p[(size_t)csr_src[j] * D + f] << 16);
    float a = ((a0 + a1) + (a2 + a3)) + ((a4 + a5) + (a6 + a7));
    size_t o = (size_t)g * D + f;
    float v = pre[o] + a * invdeg[g];
    if (RELU) v = fmaxf(v, 0.f);
    out[o] = v;
}

extern "C" void kernel_launch(void* const* d_in, const int* in_sizes, int n_in,
                              void* d_out, int out_size, void* d_ws, size_t ws_size,
                              hipStream_t stream) {
    const float* x        = (const float*)d_in[0];
    const int*   edge_src = (const int*)d_in[1];
    const int*   edge_dst = (const int*)d_in[2];
    const float* Ws1 = (const float*)d_in[3];
    const float* Wn1 = (const float*)d_in[4];
    const float* b1  = (const float*)d_in[5];
    const float* Ws2 = (const float*)d_in[6];
    const float* Wn2 = (const float*)d_in[7];
    const float* b2  = (const float*)d_in[8];
    const float* Ws3 = (const float*)d_in[9];
    const float* Wn3 = (const float*)d_in[10];
    const float* b3  = (const float*)d_in[11];
    float* out = (float*)d_out;

    const int IN = 128, HID = 32;
    const int n_nodes = in_sizes[0] / IN;
    const int n_edges = in_sizes[1];
    const int nbuk = (n_nodes + (1 << BSH) - 1) >> BSH;   // 196
    const int ch   = (n_edges + NBLK - 1) / NBLK;         // 6250

    char* wsb = (char*)d_ws;
    size_t off = 0;
    auto alloc = [&](size_t bytes) { char* r = wsb + off; off = (off + bytes + 255) & ~(size_t)255; return r; };
    int*   startp = (int*)alloc(((size_t)n_nodes + 1) * sizeof(int));
    float* invdeg = (float*)alloc((size_t)n_nodes * sizeof(float));
    int*   csr    = (int*)alloc((size_t)n_edges * sizeof(int));
    int*   hist   = (int*)alloc((size_t)nbuk * NBLK * sizeof(int));
    int*   buktot = (int*)alloc(256 * sizeof(int));
    int*   bukoff = (int*)alloc(257 * sizeof(int));
    float* B0     = (float*)alloc((size_t)n_nodes * HID * sizeof(float));    // pre (fp32)
    unsigned short* B1 = (unsigned short*)alloc((size_t)n_nodes * HID * 2);  // p (bf16)
    float* B3     = (float*)alloc((size_t)n_nodes * HID * sizeof(float));    // h (fp32)
    unsigned* pairs = (unsigned*)B0;   // CSR build fully precedes proj1 (6.4MB < B0)

    const int gP     = (n_nodes + 63) / 64;      // proj NT=64
    const int gGat32 = (n_nodes + 7) / 8;        // 8 nodes/block
    const int gGat16 = (n_nodes + 15) / 16;      // 16 nodes/block

    // ---- CSR build: hist -> hierarchical scan -> partition -> per-bucket build ----
    hist_kernel   <<<NBLK, BLOCK, 0, stream>>>(edge_dst, hist, n_edges, nbuk, ch);
    scanBlk_kernel<<<nbuk, BLOCK, 0, stream>>>(hist, buktot);
    scanBuk_kernel<<<1, BLOCK, 0, stream>>>(buktot, bukoff, nbuk, startp, n_nodes, n_edges);
    part_kernel   <<<NBLK, BLOCK, 0, stream>>>(edge_src, edge_dst, hist, bukoff, pairs, n_edges, nbuk, ch);
    build_kernel  <<<nbuk, BLOCK, 0, stream>>>(pairs, bukoff, startp, invdeg, csr, n_nodes);

    // ---- layer 1: 128 -> 32, relu ----
    proj_reg<128, 32, 8, 2><<<gP, BLOCK, 0, stream>>>(x, Ws1, Wn1, b1, B0, B1, n_nodes);
    gather_kernel<32, true><<<gGat32, BLOCK, 0, stream>>>(B1, csr, startp, B0, invdeg, B3, n_nodes);

    // ---- layer 2: 32 -> 32, relu ----
    proj_reg<32, 32, 8, 2><<<gP, BLOCK, 0, stream>>>(B3, Ws2, Wn2, b2, B0, B1, n_nodes);
    gather_kernel<32, true><<<gGat32, BLOCK, 0, stream>>>(B1, csr, startp, B0, invdeg, B3, n_nodes);

    // ---- layer 3: 32 -> 16, no relu ----
    proj_reg<32, 16, 4, 2><<<gP, BLOCK, 0, stream>>>(B3, Ws3, Wn3, b3, B0, B1, n_nodes);
    gather_kernel<16, false><<<gGat16, BLOCK, 0, stream>>>(B1, csr, startp, B0, invdeg, out, n_nodes);
}

// Round 18
// 190.475 us; speedup vs baseline: 3.9606x; 1.0306x over previous
//
#include <hip/hip_runtime.h>

// GraphSAGE 3-layer (mean agg), N=100000, E=1600000, 128->32->32->16.
// Round 18 = round 17 + MFMA projection. Seven VALU proj variants all pinned
// at 41-45us: the W-read is ~1B/FLOP vs the CU's 0.5B/FLOP LDS balance ->
// structurally LDS-bound. Switch to mfma_f32_16x16x32_bf16: weights pre-
// transposed to bf16 tables (prep kernel, L2-resident, read as 16B b-frags
// from global -> proj has NO LDS and NO barriers), x converted to bf16
// in-register, h stored bf16 by gather for layers 2/3.
// Fragment layouts per HW-verified m89/m156: A row=l&15 k=(l>>4)*8+j;
// B col=l&15 same k; C col=l&15 node=(l>>4)*4+reg.

#define BLOCK 256
#define NBLK 256            // blocks for hist/part passes
#define BSH 9               // 512 nodes per bucket
#define CAP 12288           // max edges per bucket staged in LDS

typedef __attribute__((ext_vector_type(8))) short bf16x8;
typedef __attribute__((ext_vector_type(4))) float f32x4;

__device__ __forceinline__ unsigned pack_bf16(float a, float b) {
    unsigned ua = __float_as_uint(a); ua = (ua + 0x7fffu + ((ua >> 16) & 1u)) >> 16;
    unsigned ub = __float_as_uint(b); ub = (ub + 0x7fffu + ((ub >> 16) & 1u)) >> 16;
    return ua | (ub << 16);
}
__device__ __forceinline__ unsigned short bf16r(float f) {
    unsigned u = __float_as_uint(f);
    return (unsigned short)((u + 0x7fffu + ((u >> 16) & 1u)) >> 16);
}

// ---------------- phase 1: per-(bucket,block) histogram of dst ----------------
__global__ void hist_kernel(const int* __restrict__ dst, int* __restrict__ hist,
                            int n_edges, int nbuk, int ch) {
    __shared__ int cnt[256];
    int tid = threadIdx.x;
    for (int i = tid; i < nbuk; i += BLOCK) cnt[i] = 0;
    __syncthreads();
    int e0 = blockIdx.x * ch;
    int e1 = e0 + ch; if (e1 > n_edges) e1 = n_edges;
    for (int e = e0 + tid; e < e1; e += BLOCK)
        atomicAdd(&cnt[dst[e] >> BSH], 1);
    __syncthreads();
    for (int i = tid; i < nbuk; i += BLOCK)
        hist[i * NBLK + blockIdx.x] = cnt[i];
}

// ---------------- phase 2a: per-bucket exclusive scan of its 256 block-counts ----------------
__global__ void scanBlk_kernel(int* __restrict__ hist, int* __restrict__ buktot) {
    int b = blockIdx.x;
    int tid = threadIdx.x;
    int orig = hist[b * NBLK + tid];
    int v = orig;
    int lane = tid & 63, w = tid >> 6;
#pragma unroll
    for (int off = 1; off < 64; off <<= 1) {
        int u = __shfl_up(v, off);
        if (lane >= off) v += u;
    }
    __shared__ int wps[4];
    if (lane == 63) wps[w] = v;
    __syncthreads();
    int wadd = 0;
    for (int k = 0; k < w; ++k) wadd += wps[k];
    int excl = v - orig + wadd;
    hist[b * NBLK + tid] = excl;
    if (tid == 255) buktot[b] = excl + orig;
}

// ---------------- phase 2b: exclusive scan of bucket totals (1 block) ----------------
__global__ void scanBuk_kernel(const int* __restrict__ buktot, int* __restrict__ bukoff,
                               int nbuk, int* __restrict__ startp, int n_nodes, int n_edges) {
    int tid = threadIdx.x;
    int orig = (tid < nbuk) ? buktot[tid] : 0;
    int v = orig;
    int lane = tid & 63, w = tid >> 6;
#pragma unroll
    for (int off = 1; off < 64; off <<= 1) {
        int u = __shfl_up(v, off);
        if (lane >= off) v += u;
    }
    __shared__ int wps[4];
    if (lane == 63) wps[w] = v;
    __syncthreads();
    int wadd = 0;
    for (int k = 0; k < w; ++k) wadd += wps[k];
    int excl = v - orig + wadd;
    if (tid < nbuk) bukoff[tid] = excl;
    if (tid == 0) { bukoff[nbuk] = n_edges; startp[n_nodes] = n_edges; }
}

// ---------------- phase 3: partition packed (src|dl<<20) bucket-contiguously ----------------
__global__ void part_kernel(const int* __restrict__ src, const int* __restrict__ dst,
                            const int* __restrict__ hist, const int* __restrict__ bukoff,
                            unsigned* __restrict__ pairs, int n_edges, int nbuk, int ch) {
    __shared__ int base[256];
    __shared__ int cnt[256];
    int tid = threadIdx.x;
    for (int i = tid; i < nbuk; i += BLOCK) {
        base[i] = hist[i * NBLK + blockIdx.x] + bukoff[i];
        cnt[i] = 0;
    }
    __syncthreads();
    int e0 = blockIdx.x * ch;
    int e1 = e0 + ch; if (e1 > n_edges) e1 = n_edges;
    for (int e = e0 + tid; e < e1; e += BLOCK) {
        int d = dst[e];
        int b = d >> BSH;
        unsigned dl = (unsigned)(d & ((1 << BSH) - 1));
        int r = atomicAdd(&cnt[b], 1);
        pairs[base[b] + r] = (unsigned)src[e] | (dl << 20);
    }
}

// ---------------- phase 4: per-bucket CSR build in LDS ----------------
__global__ void build_kernel(const unsigned* __restrict__ pairs, const int* __restrict__ bukoff,
                             int* __restrict__ start, float* __restrict__ invdeg,
                             int* __restrict__ csr_src, int n_nodes) {
    __shared__ int deg[512];
    __shared__ int lst[512];
    __shared__ int cur[512];
    __shared__ int wps[4];
    __shared__ int scsr[CAP];

    int b = blockIdx.x;
    int tid = threadIdx.x;
    int e0 = bukoff[b];
    int e1 = bukoff[b + 1];
    int lo = b << BSH;
    int hi = lo + (1 << BSH); if (hi > n_nodes) hi = n_nodes;
    int nn = hi - lo;
    int ne = e1 - e0;

    for (int i = tid; i < 512; i += BLOCK) deg[i] = 0;
    __syncthreads();
    for (int i = e0 + tid; i < e1; i += BLOCK)
        atomicAdd(&deg[pairs[i] >> 20], 1);
    __syncthreads();

    int d0 = deg[2 * tid], d1 = deg[2 * tid + 1];
    int s = d0 + d1;
    int lane = tid & 63, w = tid >> 6;
    int v = s;
#pragma unroll
    for (int off = 1; off < 64; off <<= 1) {
        int u = __shfl_up(v, off);
        if (lane >= off) v += u;
    }
    if (lane == 63) wps[w] = v;
    __syncthreads();
    int wb = 0;
    for (int k = 0; k < w; ++k) wb += wps[k];
    int excl = wb + v - s;
    lst[2 * tid] = excl;
    lst[2 * tid + 1] = excl + d0;
    cur[2 * tid] = 0;
    cur[2 * tid + 1] = 0;
    __syncthreads();

    for (int i = tid; i < nn; i += BLOCK) {
        start[lo + i] = e0 + lst[i];
        int d = deg[i];
        invdeg[lo + i] = 1.0f / (float)(d < 1 ? 1 : d);
    }

    if (ne <= CAP) {
        for (int i = e0 + tid; i < e1; i += BLOCK) {
            unsigned pr = pairs[i];
            int dl = pr >> 20;
            int sl = lst[dl] + atomicAdd(&cur[dl], 1);
            scsr[sl] = (int)(pr & 0xFFFFFu);
        }
        __syncthreads();
        for (int i = tid; i < ne; i += BLOCK) csr_src[e0 + i] = scsr[i];
    } else {
        for (int i = e0 + tid; i < e1; i += BLOCK) {
            unsigned pr = pairs[i];
            int dl = pr >> 20;
            int sl = lst[dl] + atomicAdd(&cur[dl], 1);
            csr_src[e0 + sl] = (int)(pr & 0xFFFFFu);
        }
    }
}

// ---------------- weight prep: transpose + bf16 (once per call, tiny) ----------------
// Wt1[64][128]: o<32 -> Ws1[k][o], else Wn1[k][o-32].  Wt2[64][32], Wt3[32][32].
__global__ void prep_kernel(const float* __restrict__ Ws1, const float* __restrict__ Wn1,
                            const float* __restrict__ Ws2, const float* __restrict__ Wn2,
                            const float* __restrict__ Ws3, const float* __restrict__ Wn3,
                            unsigned short* __restrict__ Wt1,
                            unsigned short* __restrict__ Wt2,
                            unsigned short* __restrict__ Wt3) {
    int stride = gridDim.x * BLOCK;
    int t0 = blockIdx.x * BLOCK + threadIdx.x;
    for (int i = t0; i < 64 * 128; i += stride) {
        int o = i / 128, k = i % 128;
        float v = (o < 32) ? Ws1[k * 32 + o] : Wn1[k * 32 + (o - 32)];
        Wt1[i] = bf16r(v);
    }
    for (int i = t0; i < 64 * 32; i += stride) {
        int o = i / 32, k = i % 32;
        float v = (o < 32) ? Ws2[k * 32 + o] : Wn2[k * 32 + (o - 32)];
        Wt2[i] = bf16r(v);
    }
    for (int i = t0; i < 32 * 32; i += stride) {
        int o = i / 32, k = i % 32;
        float v = (o < 16) ? Ws3[k * 16 + o] : Wn3[k * 16 + (o - 16)];
        Wt3[i] = bf16r(v);
    }
}

// ---------------- layer-1 MFMA projection: pre = x@Ws+b (fp32); p = x@Wn (bf16) ----------------
// 4 waves/block, 16 nodes/wave, K-loop 4 x 32. No LDS, no barriers.
__global__ __launch_bounds__(256, 4)
void proj1_mfma(const float* __restrict__ x,
                const unsigned short* __restrict__ Wt,   // [64][128] bf16
                const float* __restrict__ bias,          // [32]
                float* __restrict__ pre,                 // [N][32] fp32
                unsigned short* __restrict__ p,          // [N][32] bf16
                int n_nodes) {
    int tid = threadIdx.x;
    int wv = tid >> 6, l = tid & 63;
    int col = l & 15, kg = l >> 4;
    int node0 = blockIdx.x * 64 + wv * 16;

    int arow = node0 + col;
    if (arow >= n_nodes) arow = n_nodes - 1;
    const float* xr = x + (size_t)arow * 128 + kg * 8;

    f32x4 acc[4];
#pragma unroll
    for (int t = 0; t < 4; ++t) acc[t] = (f32x4){0.f, 0.f, 0.f, 0.f};

#pragma unroll
    for (int ks = 0; ks < 4; ++ks) {
        float4 f0 = *reinterpret_cast<const float4*>(xr + ks * 32);
        float4 f1 = *reinterpret_cast<const float4*>(xr + ks * 32 + 4);
        union { bf16x8 v; unsigned u[4]; } A;
        A.u[0] = pack_bf16(f0.x, f0.y);
        A.u[1] = pack_bf16(f0.z, f0.w);
        A.u[2] = pack_bf16(f1.x, f1.y);
        A.u[3] = pack_bf16(f1.z, f1.w);
#pragma unroll
        for (int t = 0; t < 4; ++t) {
            bf16x8 B = *reinterpret_cast<const bf16x8*>(
                Wt + (size_t)(t * 16 + col) * 128 + ks * 32 + kg * 8);
            acc[t] = __builtin_amdgcn_mfma_f32_16x16x32_bf16(A.v, B, acc[t], 0, 0, 0);
        }
    }

    int nodeb = node0 + kg * 4;
#pragma unroll
    for (int t = 0; t < 4; ++t) {
        int out = t * 16 + col;
#pragma unroll
        for (int r = 0; r < 4; ++r) {
            int node = nodeb + r;
            if (node >= n_nodes) continue;
            if (t < 2) {
                pre[(size_t)node * 32 + out] = acc[t][r] + bias[out];
            } else {
                p[(size_t)node * 32 + (out - 32)] = bf16r(acc[t][r]);
            }
        }
    }
}

// ---------------- layer-2/3 MFMA projection (DIN=32, h bf16 input) ----------------
template<int DOUT>
__global__ __launch_bounds__(256, 4)
void proj23_mfma(const unsigned short* __restrict__ h,   // [N][32] bf16
                 const unsigned short* __restrict__ Wt,  // [2*DOUT][32] bf16
                 const float* __restrict__ bias,         // [DOUT]
                 float* __restrict__ pre,                // [N][DOUT] fp32
                 unsigned short* __restrict__ p,         // [N][DOUT] bf16
                 int n_nodes) {
    constexpr int NTILE = DOUT / 8;      // 4 (DOUT=32) or 2 (DOUT=16)
    int tid = threadIdx.x;
    int wv = tid >> 6, l = tid & 63;
    int col = l & 15, kg = l >> 4;
    int node0 = blockIdx.x * 64 + wv * 16;

    int arow = node0 + col;
    if (arow >= n_nodes) arow = n_nodes - 1;
    bf16x8 A = *reinterpret_cast<const bf16x8*>(h + (size_t)arow * 32 + kg * 8);

    f32x4 acc[NTILE];
#pragma unroll
    for (int t = 0; t < NTILE; ++t) acc[t] = (f32x4){0.f, 0.f, 0.f, 0.f};

#pragma unroll
    for (int t = 0; t < NTILE; ++t) {
        bf16x8 B = *reinterpret_cast<const bf16x8*>(
            Wt + (size_t)(t * 16 + col) * 32 + kg * 8);
        acc[t] = __builtin_amdgcn_mfma_f32_16x16x32_bf16(A, B, acc[t], 0, 0, 0);
    }

    int nodeb = node0 + kg * 4;
#pragma unroll
    for (int t = 0; t < NTILE; ++t) {
        int out = t * 16 + col;
#pragma unroll
        for (int r = 0; r < 4; ++r) {
            int node = nodeb + r;
            if (node >= n_nodes) continue;
            if (out < DOUT) {
                pre[(size_t)node * DOUT + out] = acc[t][r] + bias[out];
            } else {
                p[(size_t)node * DOUT + (out - DOUT)] = bf16r(acc[t][r]);
            }
        }
    }
}

// ---------------- feature-parallel bf16 gather + finalize (no reduce) ----------------
template<int D, bool RELU, bool BF16OUT>
__global__ void gather_kernel(const unsigned short* __restrict__ p,
                              const int* __restrict__ csr_src,
                              const int* __restrict__ start,
                              const float* __restrict__ pre,
                              const float* __restrict__ invdeg,
                              void* __restrict__ outv,
                              int n_nodes) {
    constexpr int NPW = 64 / D;
    int wave = threadIdx.x >> 6;
    int lane = threadIdx.x & 63;
    int g = (blockIdx.x * (blockDim.x >> 6) + wave) * NPW + lane / D;
    int f = lane % D;
    if (g >= n_nodes) return;
    int s0 = start[g];
    int s1 = start[g + 1];
    float a0 = 0.f, a1 = 0.f, a2 = 0.f, a3 = 0.f;
    float a4 = 0.f, a5 = 0.f, a6 = 0.f, a7 = 0.f;
    int j = s0;
    for (; j + 8 <= s1; j += 8) {
        int c0 = csr_src[j + 0], c1 = csr_src[j + 1];
        int c2 = csr_src[j + 2], c3 = csr_src[j + 3];
        int c4 = csr_src[j + 4], c5 = csr_src[j + 5];
        int c6 = csr_src[j + 6], c7 = csr_src[j + 7];
        a0 += __uint_as_float((unsigned)p[(size_t)c0 * D + f] << 16);
        a1 += __uint_as_float((unsigned)p[(size_t)c1 * D + f] << 16);
        a2 += __uint_as_float((unsigned)p[(size_t)c2 * D + f] << 16);
        a3 += __uint_as_float((unsigned)p[(size_t)c3 * D + f] << 16);
        a4 += __uint_as_float((unsigned)p[(size_t)c4 * D + f] << 16);
        a5 += __uint_as_float((unsigned)p[(size_t)c5 * D + f] << 16);
        a6 += __uint_as_float((unsigned)p[(size_t)c6 * D + f] << 16);
        a7 += __uint_as_float((unsigned)p[(size_t)c7 * D + f] << 16);
    }
    for (; j + 2 <= s1; j += 2) {
        int c0 = csr_src[j], c1 = csr_src[j + 1];
        a0 += __uint_as_float((unsigned)p[(size_t)c0 * D + f] << 16);
        a1 += __uint_as_float((unsigned)p[(size_t)c1 * D + f] << 16);
    }
    if (j < s1)
        a2 += __uint_as_float((unsigned)p[(size_t)csr_src[j] * D + f] << 16);
    float a = ((a0 + a1) + (a2 + a3)) + ((a4 + a5) + (a6 + a7));
    size_t o = (size_t)g * D + f;
    float v = pre[o] + a * invdeg[g];
    if (RELU) v = fmaxf(v, 0.f);
    if (BF16OUT) {
        ((unsigned short*)outv)[o] = bf16r(v);
    } else {
        ((float*)outv)[o] = v;
    }
}

extern "C" void kernel_launch(void* const* d_in, const int* in_sizes, int n_in,
                              void* d_out, int out_size, void* d_ws, size_t ws_size,
                              hipStream_t stream) {
    const float* x        = (const float*)d_in[0];
    const int*   edge_src = (const int*)d_in[1];
    const int*   edge_dst = (const int*)d_in[2];
    const float* Ws1 = (const float*)d_in[3];
    const float* Wn1 = (const float*)d_in[4];
    const float* b1  = (const float*)d_in[5];
    const float* Ws2 = (const float*)d_in[6];
    const float* Wn2 = (const float*)d_in[7];
    const float* b2  = (const float*)d_in[8];
    const float* Ws3 = (const float*)d_in[9];
    const float* Wn3 = (const float*)d_in[10];
    const float* b3  = (const float*)d_in[11];
    float* out = (float*)d_out;

    const int IN = 128, HID = 32;
    const int n_nodes = in_sizes[0] / IN;
    const int n_edges = in_sizes[1];
    const int nbuk = (n_nodes + (1 << BSH) - 1) >> BSH;   // 196
    const int ch   = (n_edges + NBLK - 1) / NBLK;         // 6250

    char* wsb = (char*)d_ws;
    size_t off = 0;
    auto alloc = [&](size_t bytes) { char* r = wsb + off; off = (off + bytes + 255) & ~(size_t)255; return r; };
    int*   startp = (int*)alloc(((size_t)n_nodes + 1) * sizeof(int));
    float* invdeg = (float*)alloc((size_t)n_nodes * sizeof(float));
    int*   csr    = (int*)alloc((size_t)n_edges * sizeof(int));
    int*   hist   = (int*)alloc((size_t)nbuk * NBLK * sizeof(int));
    int*   buktot = (int*)alloc(256 * sizeof(int));
    int*   bukoff = (int*)alloc(257 * sizeof(int));
    unsigned short* Wt1 = (unsigned short*)alloc(64 * 128 * 2);
    unsigned short* Wt2 = (unsigned short*)alloc(64 * 32 * 2);
    unsigned short* Wt3 = (unsigned short*)alloc(32 * 32 * 2);
    float* B0     = (float*)alloc((size_t)n_nodes * HID * sizeof(float));    // pre (fp32)
    unsigned short* B1 = (unsigned short*)alloc((size_t)n_nodes * HID * 2);  // p (bf16)
    unsigned short* B3 = (unsigned short*)alloc((size_t)n_nodes * HID * 2);  // h (bf16)
    unsigned* pairs = (unsigned*)B0;   // CSR build fully precedes proj1 (6.4MB < B0)

    const int gP     = (n_nodes + 63) / 64;      // proj: 64 nodes/block
    const int gGat32 = (n_nodes + 7) / 8;        // 8 nodes/block
    const int gGat16 = (n_nodes + 15) / 16;      // 16 nodes/block

    // ---- weight prep + CSR build ----
    prep_kernel   <<<64, BLOCK, 0, stream>>>(Ws1, Wn1, Ws2, Wn2, Ws3, Wn3, Wt1, Wt2, Wt3);
    hist_kernel   <<<NBLK, BLOCK, 0, stream>>>(edge_dst, hist, n_edges, nbuk, ch);
    scanBlk_kernel<<<nbuk, BLOCK, 0, stream>>>(hist, buktot);
    scanBuk_kernel<<<1, BLOCK, 0, stream>>>(buktot, bukoff, nbuk, startp, n_nodes, n_edges);
    part_kernel   <<<NBLK, BLOCK, 0, stream>>>(edge_src, edge_dst, hist, bukoff, pairs, n_edges, nbuk, ch);
    build_kernel  <<<nbuk, BLOCK, 0, stream>>>(pairs, bukoff, startp, invdeg, csr, n_nodes);

    // ---- layer 1: 128 -> 32, relu ----
    proj1_mfma<<<gP, BLOCK, 0, stream>>>(x, Wt1, b1, B0, B1, n_nodes);
    gather_kernel<32, true, true><<<gGat32, BLOCK, 0, stream>>>(B1, csr, startp, B0, invdeg, B3, n_nodes);

    // ---- layer 2: 32 -> 32, relu ----
    proj23_mfma<32><<<gP, BLOCK, 0, stream>>>(B3, Wt2, b2, B0, B1, n_nodes);
    gather_kernel<32, true, true><<<gGat32, BLOCK, 0, stream>>>(B1, csr, startp, B0, invdeg, B3, n_nodes);

    // ---- layer 3: 32 -> 16, no relu ----
    proj23_mfma<16><<<gP, BLOCK, 0, stream>>>(B3, Wt3, b3, B0, B1, n_nodes);
    gather_kernel<16, false, false><<<gGat16, BLOCK, 0, stream>>>(B1, csr, startp, B0, invdeg, out, n_nodes);
}

// Round 19
// 188.031 us; speedup vs baseline: 4.0121x; 1.0130x over previous
//
#include <hip/hip_runtime.h>

// GraphSAGE 3-layer (mean agg), N=100000, E=1600000, 128->32->32->16.
// Round 19 = round 18 + (a) proj1 fused into hist as role-split grid (proj1
// is independent of the CSR chain -> its ~13us hides under hist; pairs no
// longer aliases B0), (b) bf16 pre everywhere (saves ~38MB traffic),
// (c) gather unroll 16 (16 outstanding loads, mean deg=16).

#define BLOCK 256
#define NBLK 256            // blocks for hist/part passes
#define BSH 9               // 512 nodes per bucket
#define CAP 12288           // max edges per bucket staged in LDS

typedef __attribute__((ext_vector_type(8))) short bf16x8;
typedef __attribute__((ext_vector_type(4))) float f32x4;

__device__ __forceinline__ unsigned pack_bf16(float a, float b) {
    unsigned ua = __float_as_uint(a); ua = (ua + 0x7fffu + ((ua >> 16) & 1u)) >> 16;
    unsigned ub = __float_as_uint(b); ub = (ub + 0x7fffu + ((ub >> 16) & 1u)) >> 16;
    return ua | (ub << 16);
}
__device__ __forceinline__ unsigned short bf16r(float f) {
    unsigned u = __float_as_uint(f);
    return (unsigned short)((u + 0x7fffu + ((u >> 16) & 1u)) >> 16);
}
__device__ __forceinline__ float bf2f(unsigned short u) {
    return __uint_as_float((unsigned)u << 16);
}

// ---------------- weight prep: transpose + bf16 (once per call, tiny) ----------------
__global__ void prep_kernel(const float* __restrict__ Ws1, const float* __restrict__ Wn1,
                            const float* __restrict__ Ws2, const float* __restrict__ Wn2,
                            const float* __restrict__ Ws3, const float* __restrict__ Wn3,
                            unsigned short* __restrict__ Wt1,
                            unsigned short* __restrict__ Wt2,
                            unsigned short* __restrict__ Wt3) {
    int stride = gridDim.x * BLOCK;
    int t0 = blockIdx.x * BLOCK + threadIdx.x;
    for (int i = t0; i < 64 * 128; i += stride) {
        int o = i / 128, k = i % 128;
        float v = (o < 32) ? Ws1[k * 32 + o] : Wn1[k * 32 + (o - 32)];
        Wt1[i] = bf16r(v);
    }
    for (int i = t0; i < 64 * 32; i += stride) {
        int o = i / 32, k = i % 32;
        float v = (o < 32) ? Ws2[k * 32 + o] : Wn2[k * 32 + (o - 32)];
        Wt2[i] = bf16r(v);
    }
    for (int i = t0; i < 32 * 32; i += stride) {
        int o = i / 32, k = i % 32;
        float v = (o < 16) ? Ws3[k * 16 + o] : Wn3[k * 16 + (o - 16)];
        Wt3[i] = bf16r(v);
    }
}

// ---------------- stage1: role-split hist (blocks 0..nHist) + proj1 MFMA ----------------
__global__ __launch_bounds__(256, 4)
void stage1_kernel(const int* __restrict__ dst, int* __restrict__ hist,
                   int n_edges, int nbuk, int ch,
                   const float* __restrict__ x,
                   const unsigned short* __restrict__ Wt,   // [64][128] bf16
                   const float* __restrict__ bias,          // [32]
                   unsigned short* __restrict__ pre,        // [N][32] bf16
                   unsigned short* __restrict__ p,          // [N][32] bf16
                   int n_nodes, int nHist) {
    __shared__ int cnt[256];
    int bid = blockIdx.x;
    int tid = threadIdx.x;

    if (bid < nHist) {
        // ---- histogram role ----
        for (int i = tid; i < nbuk; i += BLOCK) cnt[i] = 0;
        __syncthreads();
        int e0 = bid * ch;
        int e1 = e0 + ch; if (e1 > n_edges) e1 = n_edges;
        for (int e = e0 + tid; e < e1; e += BLOCK)
            atomicAdd(&cnt[dst[e] >> BSH], 1);
        __syncthreads();
        for (int i = tid; i < nbuk; i += BLOCK)
            hist[i * NBLK + bid] = cnt[i];
        return;
    }

    // ---- proj1 MFMA role: 4 waves, 16 nodes/wave, K = 4 x 32 ----
    int pb = bid - nHist;
    int wv = tid >> 6, l = tid & 63;
    int col = l & 15, kg = l >> 4;
    int node0 = pb * 64 + wv * 16;

    int arow = node0 + col;
    if (arow >= n_nodes) arow = n_nodes - 1;
    const float* xr = x + (size_t)arow * 128 + kg * 8;

    f32x4 acc[4];
#pragma unroll
    for (int t = 0; t < 4; ++t) acc[t] = (f32x4){0.f, 0.f, 0.f, 0.f};

#pragma unroll
    for (int ks = 0; ks < 4; ++ks) {
        float4 f0 = *reinterpret_cast<const float4*>(xr + ks * 32);
        float4 f1 = *reinterpret_cast<const float4*>(xr + ks * 32 + 4);
        union { bf16x8 v; unsigned u[4]; } A;
        A.u[0] = pack_bf16(f0.x, f0.y);
        A.u[1] = pack_bf16(f0.z, f0.w);
        A.u[2] = pack_bf16(f1.x, f1.y);
        A.u[3] = pack_bf16(f1.z, f1.w);
#pragma unroll
        for (int t = 0; t < 4; ++t) {
            bf16x8 B = *reinterpret_cast<const bf16x8*>(
                Wt + (size_t)(t * 16 + col) * 128 + ks * 32 + kg * 8);
            acc[t] = __builtin_amdgcn_mfma_f32_16x16x32_bf16(A.v, B, acc[t], 0, 0, 0);
        }
    }

    int nodeb = node0 + kg * 4;
#pragma unroll
    for (int t = 0; t < 4; ++t) {
        int out = t * 16 + col;
#pragma unroll
        for (int r = 0; r < 4; ++r) {
            int node = nodeb + r;
            if (node >= n_nodes) continue;
            if (t < 2) {
                pre[(size_t)node * 32 + out] = bf16r(acc[t][r] + bias[out]);
            } else {
                p[(size_t)node * 32 + (out - 32)] = bf16r(acc[t][r]);
            }
        }
    }
}

// ---------------- phase 2a: per-bucket exclusive scan of its 256 block-counts ----------------
__global__ void scanBlk_kernel(int* __restrict__ hist, int* __restrict__ buktot) {
    int b = blockIdx.x;
    int tid = threadIdx.x;
    int orig = hist[b * NBLK + tid];
    int v = orig;
    int lane = tid & 63, w = tid >> 6;
#pragma unroll
    for (int off = 1; off < 64; off <<= 1) {
        int u = __shfl_up(v, off);
        if (lane >= off) v += u;
    }
    __shared__ int wps[4];
    if (lane == 63) wps[w] = v;
    __syncthreads();
    int wadd = 0;
    for (int k = 0; k < w; ++k) wadd += wps[k];
    int excl = v - orig + wadd;
    hist[b * NBLK + tid] = excl;
    if (tid == 255) buktot[b] = excl + orig;
}

// ---------------- phase 2b: exclusive scan of bucket totals (1 block) ----------------
__global__ void scanBuk_kernel(const int* __restrict__ buktot, int* __restrict__ bukoff,
                               int nbuk, int* __restrict__ startp, int n_nodes, int n_edges) {
    int tid = threadIdx.x;
    int orig = (tid < nbuk) ? buktot[tid] : 0;
    int v = orig;
    int lane = tid & 63, w = tid >> 6;
#pragma unroll
    for (int off = 1; off < 64; off <<= 1) {
        int u = __shfl_up(v, off);
        if (lane >= off) v += u;
    }
    __shared__ int wps[4];
    if (lane == 63) wps[w] = v;
    __syncthreads();
    int wadd = 0;
    for (int k = 0; k < w; ++k) wadd += wps[k];
    int excl = v - orig + wadd;
    if (tid < nbuk) bukoff[tid] = excl;
    if (tid == 0) { bukoff[nbuk] = n_edges; startp[n_nodes] = n_edges; }
}

// ---------------- phase 3: partition packed (src|dl<<20) bucket-contiguously ----------------
__global__ void part_kernel(const int* __restrict__ src, const int* __restrict__ dst,
                            const int* __restrict__ hist, const int* __restrict__ bukoff,
                            unsigned* __restrict__ pairs, int n_edges, int nbuk, int ch) {
    __shared__ int base[256];
    __shared__ int cnt[256];
    int tid = threadIdx.x;
    for (int i = tid; i < nbuk; i += BLOCK) {
        base[i] = hist[i * NBLK + blockIdx.x] + bukoff[i];
        cnt[i] = 0;
    }
    __syncthreads();
    int e0 = blockIdx.x * ch;
    int e1 = e0 + ch; if (e1 > n_edges) e1 = n_edges;
    for (int e = e0 + tid; e < e1; e += BLOCK) {
        int d = dst[e];
        int b = d >> BSH;
        unsigned dl = (unsigned)(d & ((1 << BSH) - 1));
        int r = atomicAdd(&cnt[b], 1);
        pairs[base[b] + r] = (unsigned)src[e] | (dl << 20);
    }
}

// ---------------- phase 4: per-bucket CSR build in LDS ----------------
__global__ void build_kernel(const unsigned* __restrict__ pairs, const int* __restrict__ bukoff,
                             int* __restrict__ start, float* __restrict__ invdeg,
                             int* __restrict__ csr_src, int n_nodes) {
    __shared__ int deg[512];
    __shared__ int lst[512];
    __shared__ int cur[512];
    __shared__ int wps[4];
    __shared__ int scsr[CAP];

    int b = blockIdx.x;
    int tid = threadIdx.x;
    int e0 = bukoff[b];
    int e1 = bukoff[b + 1];
    int lo = b << BSH;
    int hi = lo + (1 << BSH); if (hi > n_nodes) hi = n_nodes;
    int nn = hi - lo;
    int ne = e1 - e0;

    for (int i = tid; i < 512; i += BLOCK) deg[i] = 0;
    __syncthreads();
    for (int i = e0 + tid; i < e1; i += BLOCK)
        atomicAdd(&deg[pairs[i] >> 20], 1);
    __syncthreads();

    int d0 = deg[2 * tid], d1 = deg[2 * tid + 1];
    int s = d0 + d1;
    int lane = tid & 63, w = tid >> 6;
    int v = s;
#pragma unroll
    for (int off = 1; off < 64; off <<= 1) {
        int u = __shfl_up(v, off);
        if (lane >= off) v += u;
    }
    if (lane == 63) wps[w] = v;
    __syncthreads();
    int wb = 0;
    for (int k = 0; k < w; ++k) wb += wps[k];
    int excl = wb + v - s;
    lst[2 * tid] = excl;
    lst[2 * tid + 1] = excl + d0;
    cur[2 * tid] = 0;
    cur[2 * tid + 1] = 0;
    __syncthreads();

    for (int i = tid; i < nn; i += BLOCK) {
        start[lo + i] = e0 + lst[i];
        int d = deg[i];
        invdeg[lo + i] = 1.0f / (float)(d < 1 ? 1 : d);
    }

    if (ne <= CAP) {
        for (int i = e0 + tid; i < e1; i += BLOCK) {
            unsigned pr = pairs[i];
            int dl = pr >> 20;
            int sl = lst[dl] + atomicAdd(&cur[dl], 1);
            scsr[sl] = (int)(pr & 0xFFFFFu);
        }
        __syncthreads();
        for (int i = tid; i < ne; i += BLOCK) csr_src[e0 + i] = scsr[i];
    } else {
        for (int i = e0 + tid; i < e1; i += BLOCK) {
            unsigned pr = pairs[i];
            int dl = pr >> 20;
            int sl = lst[dl] + atomicAdd(&cur[dl], 1);
            csr_src[e0 + sl] = (int)(pr & 0xFFFFFu);
        }
    }
}

// ---------------- layer-2/3 MFMA projection (DIN=32, h bf16 input) ----------------
template<int DOUT>
__global__ __launch_bounds__(256, 4)
void proj23_mfma(const unsigned short* __restrict__ h,   // [N][32] bf16
                 const unsigned short* __restrict__ Wt,  // [2*DOUT][32] bf16
                 const float* __restrict__ bias,         // [DOUT]
                 unsigned short* __restrict__ pre,       // [N][DOUT] bf16
                 unsigned short* __restrict__ p,         // [N][DOUT] bf16
                 int n_nodes) {
    constexpr int NTILE = DOUT / 8;      // 4 (DOUT=32) or 2 (DOUT=16)
    int tid = threadIdx.x;
    int wv = tid >> 6, l = tid & 63;
    int col = l & 15, kg = l >> 4;
    int node0 = blockIdx.x * 64 + wv * 16;

    int arow = node0 + col;
    if (arow >= n_nodes) arow = n_nodes - 1;
    bf16x8 A = *reinterpret_cast<const bf16x8*>(h + (size_t)arow * 32 + kg * 8);

    f32x4 acc[NTILE];
#pragma unroll
    for (int t = 0; t < NTILE; ++t) acc[t] = (f32x4){0.f, 0.f, 0.f, 0.f};

#pragma unroll
    for (int t = 0; t < NTILE; ++t) {
        bf16x8 B = *reinterpret_cast<const bf16x8*>(
            Wt + (size_t)(t * 16 + col) * 32 + kg * 8);
        acc[t] = __builtin_amdgcn_mfma_f32_16x16x32_bf16(A, B, acc[t], 0, 0, 0);
    }

    int nodeb = node0 + kg * 4;
#pragma unroll
    for (int t = 0; t < NTILE; ++t) {
        int out = t * 16 + col;
#pragma unroll
        for (int r = 0; r < 4; ++r) {
            int node = nodeb + r;
            if (node >= n_nodes) continue;
            if (out < DOUT) {
                pre[(size_t)node * DOUT + out] = bf16r(acc[t][r] + bias[out]);
            } else {
                p[(size_t)node * DOUT + (out - DOUT)] = bf16r(acc[t][r]);
            }
        }
    }
}

// ---------------- feature-parallel bf16 gather + finalize (no reduce, unroll 16) ----------------
template<int D, bool RELU, bool BF16OUT>
__global__ void gather_kernel(const unsigned short* __restrict__ p,
                              const int* __restrict__ csr_src,
                              const int* __restrict__ start,
                              const unsigned short* __restrict__ pre,  // bf16
                              const float* __restrict__ invdeg,
                              void* __restrict__ outv,
                              int n_nodes) {
    constexpr int NPW = 64 / D;
    int wave = threadIdx.x >> 6;
    int lane = threadIdx.x & 63;
    int g = (blockIdx.x * (blockDim.x >> 6) + wave) * NPW + lane / D;
    int f = lane % D;
    if (g >= n_nodes) return;
    int s0 = start[g];
    int s1 = start[g + 1];
    float a0 = 0.f, a1 = 0.f, a2 = 0.f, a3 = 0.f;
    float a4 = 0.f, a5 = 0.f, a6 = 0.f, a7 = 0.f;
    int j = s0;
    for (; j + 16 <= s1; j += 16) {
        int c[16];
#pragma unroll
        for (int q = 0; q < 16; ++q) c[q] = csr_src[j + q];
        unsigned short u[16];
#pragma unroll
        for (int q = 0; q < 16; ++q) u[q] = p[(size_t)c[q] * D + f];
        a0 += bf2f(u[0]) + bf2f(u[8]);
        a1 += bf2f(u[1]) + bf2f(u[9]);
        a2 += bf2f(u[2]) + bf2f(u[10]);
        a3 += bf2f(u[3]) + bf2f(u[11]);
        a4 += bf2f(u[4]) + bf2f(u[12]);
        a5 += bf2f(u[5]) + bf2f(u[13]);
        a6 += bf2f(u[6]) + bf2f(u[14]);
        a7 += bf2f(u[7]) + bf2f(u[15]);
    }
    for (; j + 4 <= s1; j += 4) {
        int c0 = csr_src[j], c1 = csr_src[j + 1];
        int c2 = csr_src[j + 2], c3 = csr_src[j + 3];
        a0 += bf2f(p[(size_t)c0 * D + f]);
        a1 += bf2f(p[(size_t)c1 * D + f]);
        a2 += bf2f(p[(size_t)c2 * D + f]);
        a3 += bf2f(p[(size_t)c3 * D + f]);
    }
    for (; j < s1; ++j)
        a4 += bf2f(p[(size_t)csr_src[j] * D + f]);
    float a = ((a0 + a1) + (a2 + a3)) + ((a4 + a5) + (a6 + a7));
    size_t o = (size_t)g * D + f;
    float v = bf2f(pre[o]) + a * invdeg[g];
    if (RELU) v = fmaxf(v, 0.f);
    if (BF16OUT) {
        ((unsigned short*)outv)[o] = bf16r(v);
    } else {
        ((float*)outv)[o] = v;
    }
}

extern "C" void kernel_launch(void* const* d_in, const int* in_sizes, int n_in,
                              void* d_out, int out_size, void* d_ws, size_t ws_size,
                              hipStream_t stream) {
    const float* x        = (const float*)d_in[0];
    const int*   edge_src = (const int*)d_in[1];
    const int*   edge_dst = (const int*)d_in[2];
    const float* Ws1 = (const float*)d_in[3];
    const float* Wn1 = (const float*)d_in[4];
    const float* b1  = (const float*)d_in[5];
    const float* Ws2 = (const float*)d_in[6];
    const float* Wn2 = (const float*)d_in[7];
    const float* b2  = (const float*)d_in[8];
    const float* Ws3 = (const float*)d_in[9];
    const float* Wn3 = (const float*)d_in[10];
    const float* b3  = (const float*)d_in[11];
    float* out = (float*)d_out;

    const int IN = 128, HID = 32;
    const int n_nodes = in_sizes[0] / IN;
    const int n_edges = in_sizes[1];
    const int nbuk = (n_nodes + (1 << BSH) - 1) >> BSH;   // 196
    const int ch   = (n_edges + NBLK - 1) / NBLK;         // 6250

    char* wsb = (char*)d_ws;
    size_t off = 0;
    auto alloc = [&](size_t bytes) { char* r = wsb + off; off = (off + bytes + 255) & ~(size_t)255; return r; };
    int*   startp = (int*)alloc(((size_t)n_nodes + 1) * sizeof(int));
    float* invdeg = (float*)alloc((size_t)n_nodes * sizeof(float));
    int*   csr    = (int*)alloc((size_t)n_edges * sizeof(int));
    int*   hist   = (int*)alloc((size_t)nbuk * NBLK * sizeof(int));
    int*   buktot = (int*)alloc(256 * sizeof(int));
    int*   bukoff = (int*)alloc(257 * sizeof(int));
    unsigned short* Wt1 = (unsigned short*)alloc(64 * 128 * 2);
    unsigned short* Wt2 = (unsigned short*)alloc(64 * 32 * 2);
    unsigned short* Wt3 = (unsigned short*)alloc(32 * 32 * 2);
    unsigned* pairs = (unsigned*)alloc((size_t)n_edges * sizeof(unsigned));  // no aliasing now
    unsigned short* B0 = (unsigned short*)alloc((size_t)n_nodes * HID * 2);  // pre (bf16)
    unsigned short* B1 = (unsigned short*)alloc((size_t)n_nodes * HID * 2);  // p (bf16)
    unsigned short* B3 = (unsigned short*)alloc((size_t)n_nodes * HID * 2);  // h (bf16)

    const int gP     = (n_nodes + 63) / 64;      // proj: 64 nodes/block
    const int gGat32 = (n_nodes + 7) / 8;        // 8 nodes/block
    const int gGat16 = (n_nodes + 15) / 16;      // 16 nodes/block

    // ---- prep, then stage1 = hist (256 blocks) || proj1 (gP blocks) ----
    prep_kernel  <<<64, BLOCK, 0, stream>>>(Ws1, Wn1, Ws2, Wn2, Ws3, Wn3, Wt1, Wt2, Wt3);
    stage1_kernel<<<NBLK + gP, BLOCK, 0, stream>>>(edge_dst, hist, n_edges, nbuk, ch,
                                                   x, Wt1, b1, B0, B1, n_nodes, NBLK);
    scanBlk_kernel<<<nbuk, BLOCK, 0, stream>>>(hist, buktot);
    scanBuk_kernel<<<1, BLOCK, 0, stream>>>(buktot, bukoff, nbuk, startp, n_nodes, n_edges);
    part_kernel   <<<NBLK, BLOCK, 0, stream>>>(edge_src, edge_dst, hist, bukoff, pairs, n_edges, nbuk, ch);
    build_kernel  <<<nbuk, BLOCK, 0, stream>>>(pairs, bukoff, startp, invdeg, csr, n_nodes);

    // ---- layer 1 gather: h = relu(pre + mean p) ----
    gather_kernel<32, true, true><<<gGat32, BLOCK, 0, stream>>>(B1, csr, startp, B0, invdeg, B3, n_nodes);

    // ---- layer 2: 32 -> 32, relu ----
    proj23_mfma<32><<<gP, BLOCK, 0, stream>>>(B3, Wt2, b2, B0, B1, n_nodes);
    gather_kernel<32, true, true><<<gGat32, BLOCK, 0, stream>>>(B1, csr, startp, B0, invdeg, B3, n_nodes);

    // ---- layer 3: 32 -> 16, no relu ----
    proj23_mfma<16><<<gP, BLOCK, 0, stream>>>(B3, Wt3, b3, B0, B1, n_nodes);
    gather_kernel<16, false, false><<<gGat16, BLOCK, 0, stream>>>(B1, csr, startp, B0, invdeg, out, n_nodes);
}

// Round 20
// 181.947 us; speedup vs baseline: 4.1463x; 1.0334x over previous
//
#include <hip/hip_runtime.h>

// GraphSAGE 3-layer (mean agg), N=100000, E=1600000, 128->32->32->16.
// Round 20 = round 19 + gather/proj fusion: the layer-(i+1) MFMA projection
// runs in the SAME block as the layer-i gather. Block = 16 consecutive nodes;
// phase A: feature-parallel gather -> h tile in LDS (1KB, bf16, never global);
// phase B: each wave does one 16x16x32 MFMA (t=wv) of the next projection.
// Saves the h global round-trip (25.6MB) + 2 launches. Layer-3 gather
// standalone (fp32 out). Everything else = round 19.

#define BLOCK 256
#define NBLK 256            // blocks for hist/part passes
#define BSH 9               // 512 nodes per bucket
#define CAP 12288           // max edges per bucket staged in LDS

typedef __attribute__((ext_vector_type(8))) short bf16x8;
typedef __attribute__((ext_vector_type(4))) float f32x4;

__device__ __forceinline__ unsigned pack_bf16(float a, float b) {
    unsigned ua = __float_as_uint(a); ua = (ua + 0x7fffu + ((ua >> 16) & 1u)) >> 16;
    unsigned ub = __float_as_uint(b); ub = (ub + 0x7fffu + ((ub >> 16) & 1u)) >> 16;
    return ua | (ub << 16);
}
__device__ __forceinline__ unsigned short bf16r(float f) {
    unsigned u = __float_as_uint(f);
    return (unsigned short)((u + 0x7fffu + ((u >> 16) & 1u)) >> 16);
}
__device__ __forceinline__ float bf2f(unsigned short u) {
    return __uint_as_float((unsigned)u << 16);
}

// ---------------- weight prep: transpose + bf16 (once per call, tiny) ----------------
__global__ void prep_kernel(const float* __restrict__ Ws1, const float* __restrict__ Wn1,
                            const float* __restrict__ Ws2, const float* __restrict__ Wn2,
                            const float* __restrict__ Ws3, const float* __restrict__ Wn3,
                            unsigned short* __restrict__ Wt1,
                            unsigned short* __restrict__ Wt2,
                            unsigned short* __restrict__ Wt3) {
    int stride = gridDim.x * BLOCK;
    int t0 = blockIdx.x * BLOCK + threadIdx.x;
    for (int i = t0; i < 64 * 128; i += stride) {
        int o = i / 128, k = i % 128;
        float v = (o < 32) ? Ws1[k * 32 + o] : Wn1[k * 32 + (o - 32)];
        Wt1[i] = bf16r(v);
    }
    for (int i = t0; i < 64 * 32; i += stride) {
        int o = i / 32, k = i % 32;
        float v = (o < 32) ? Ws2[k * 32 + o] : Wn2[k * 32 + (o - 32)];
        Wt2[i] = bf16r(v);
    }
    for (int i = t0; i < 32 * 32; i += stride) {
        int o = i / 32, k = i % 32;
        float v = (o < 16) ? Ws3[k * 16 + o] : Wn3[k * 16 + (o - 16)];
        Wt3[i] = bf16r(v);
    }
}

// ---------------- stage1: role-split hist (blocks 0..nHist) + proj1 MFMA ----------------
__global__ __launch_bounds__(256, 4)
void stage1_kernel(const int* __restrict__ dst, int* __restrict__ hist,
                   int n_edges, int nbuk, int ch,
                   const float* __restrict__ x,
                   const unsigned short* __restrict__ Wt,   // [64][128] bf16
                   const float* __restrict__ bias,          // [32]
                   unsigned short* __restrict__ pre,        // [N][32] bf16
                   unsigned short* __restrict__ p,          // [N][32] bf16
                   int n_nodes, int nHist) {
    __shared__ int cnt[256];
    int bid = blockIdx.x;
    int tid = threadIdx.x;

    if (bid < nHist) {
        for (int i = tid; i < nbuk; i += BLOCK) cnt[i] = 0;
        __syncthreads();
        int e0 = bid * ch;
        int e1 = e0 + ch; if (e1 > n_edges) e1 = n_edges;
        for (int e = e0 + tid; e < e1; e += BLOCK)
            atomicAdd(&cnt[dst[e] >> BSH], 1);
        __syncthreads();
        for (int i = tid; i < nbuk; i += BLOCK)
            hist[i * NBLK + bid] = cnt[i];
        return;
    }

    int pb = bid - nHist;
    int wv = tid >> 6, l = tid & 63;
    int col = l & 15, kg = l >> 4;
    int node0 = pb * 64 + wv * 16;

    int arow = node0 + col;
    if (arow >= n_nodes) arow = n_nodes - 1;
    const float* xr = x + (size_t)arow * 128 + kg * 8;

    f32x4 acc[4];
#pragma unroll
    for (int t = 0; t < 4; ++t) acc[t] = (f32x4){0.f, 0.f, 0.f, 0.f};

#pragma unroll
    for (int ks = 0; ks < 4; ++ks) {
        float4 f0 = *reinterpret_cast<const float4*>(xr + ks * 32);
        float4 f1 = *reinterpret_cast<const float4*>(xr + ks * 32 + 4);
        union { bf16x8 v; unsigned u[4]; } A;
        A.u[0] = pack_bf16(f0.x, f0.y);
        A.u[1] = pack_bf16(f0.z, f0.w);
        A.u[2] = pack_bf16(f1.x, f1.y);
        A.u[3] = pack_bf16(f1.z, f1.w);
#pragma unroll
        for (int t = 0; t < 4; ++t) {
            bf16x8 B = *reinterpret_cast<const bf16x8*>(
                Wt + (size_t)(t * 16 + col) * 128 + ks * 32 + kg * 8);
            acc[t] = __builtin_amdgcn_mfma_f32_16x16x32_bf16(A.v, B, acc[t], 0, 0, 0);
        }
    }

    int nodeb = node0 + kg * 4;
#pragma unroll
    for (int t = 0; t < 4; ++t) {
        int out = t * 16 + col;
#pragma unroll
        for (int r = 0; r < 4; ++r) {
            int node = nodeb + r;
            if (node >= n_nodes) continue;
            if (t < 2) {
                pre[(size_t)node * 32 + out] = bf16r(acc[t][r] + bias[out]);
            } else {
                p[(size_t)node * 32 + (out - 32)] = bf16r(acc[t][r]);
            }
        }
    }
}

// ---------------- phase 2a: per-bucket exclusive scan of its 256 block-counts ----------------
__global__ void scanBlk_kernel(int* __restrict__ hist, int* __restrict__ buktot) {
    int b = blockIdx.x;
    int tid = threadIdx.x;
    int orig = hist[b * NBLK + tid];
    int v = orig;
    int lane = tid & 63, w = tid >> 6;
#pragma unroll
    for (int off = 1; off < 64; off <<= 1) {
        int u = __shfl_up(v, off);
        if (lane >= off) v += u;
    }
    __shared__ int wps[4];
    if (lane == 63) wps[w] = v;
    __syncthreads();
    int wadd = 0;
    for (int k = 0; k < w; ++k) wadd += wps[k];
    int excl = v - orig + wadd;
    hist[b * NBLK + tid] = excl;
    if (tid == 255) buktot[b] = excl + orig;
}

// ---------------- phase 2b: exclusive scan of bucket totals (1 block) ----------------
__global__ void scanBuk_kernel(const int* __restrict__ buktot, int* __restrict__ bukoff,
                               int nbuk, int* __restrict__ startp, int n_nodes, int n_edges) {
    int tid = threadIdx.x;
    int orig = (tid < nbuk) ? buktot[tid] : 0;
    int v = orig;
    int lane = tid & 63, w = tid >> 6;
#pragma unroll
    for (int off = 1; off < 64; off <<= 1) {
        int u = __shfl_up(v, off);
        if (lane >= off) v += u;
    }
    __shared__ int wps[4];
    if (lane == 63) wps[w] = v;
    __syncthreads();
    int wadd = 0;
    for (int k = 0; k < w; ++k) wadd += wps[k];
    int excl = v - orig + wadd;
    if (tid < nbuk) bukoff[tid] = excl;
    if (tid == 0) { bukoff[nbuk] = n_edges; startp[n_nodes] = n_edges; }
}

// ---------------- phase 3: partition packed (src|dl<<20) bucket-contiguously ----------------
__global__ void part_kernel(const int* __restrict__ src, const int* __restrict__ dst,
                            const int* __restrict__ hist, const int* __restrict__ bukoff,
                            unsigned* __restrict__ pairs, int n_edges, int nbuk, int ch) {
    __shared__ int base[256];
    __shared__ int cnt[256];
    int tid = threadIdx.x;
    for (int i = tid; i < nbuk; i += BLOCK) {
        base[i] = hist[i * NBLK + blockIdx.x] + bukoff[i];
        cnt[i] = 0;
    }
    __syncthreads();
    int e0 = blockIdx.x * ch;
    int e1 = e0 + ch; if (e1 > n_edges) e1 = n_edges;
    for (int e = e0 + tid; e < e1; e += BLOCK) {
        int d = dst[e];
        int b = d >> BSH;
        unsigned dl = (unsigned)(d & ((1 << BSH) - 1));
        int r = atomicAdd(&cnt[b], 1);
        pairs[base[b] + r] = (unsigned)src[e] | (dl << 20);
    }
}

// ---------------- phase 4: per-bucket CSR build in LDS ----------------
__global__ void build_kernel(const unsigned* __restrict__ pairs, const int* __restrict__ bukoff,
                             int* __restrict__ start, float* __restrict__ invdeg,
                             int* __restrict__ csr_src, int n_nodes) {
    __shared__ int deg[512];
    __shared__ int lst[512];
    __shared__ int cur[512];
    __shared__ int wps[4];
    __shared__ int scsr[CAP];

    int b = blockIdx.x;
    int tid = threadIdx.x;
    int e0 = bukoff[b];
    int e1 = bukoff[b + 1];
    int lo = b << BSH;
    int hi = lo + (1 << BSH); if (hi > n_nodes) hi = n_nodes;
    int nn = hi - lo;
    int ne = e1 - e0;

    for (int i = tid; i < 512; i += BLOCK) deg[i] = 0;
    __syncthreads();
    for (int i = e0 + tid; i < e1; i += BLOCK)
        atomicAdd(&deg[pairs[i] >> 20], 1);
    __syncthreads();

    int d0 = deg[2 * tid], d1 = deg[2 * tid + 1];
    int s = d0 + d1;
    int lane = tid & 63, w = tid >> 6;
    int v = s;
#pragma unroll
    for (int off = 1; off < 64; off <<= 1) {
        int u = __shfl_up(v, off);
        if (lane >= off) v += u;
    }
    if (lane == 63) wps[w] = v;
    __syncthreads();
    int wb = 0;
    for (int k = 0; k < w; ++k) wb += wps[k];
    int excl = wb + v - s;
    lst[2 * tid] = excl;
    lst[2 * tid + 1] = excl + d0;
    cur[2 * tid] = 0;
    cur[2 * tid + 1] = 0;
    __syncthreads();

    for (int i = tid; i < nn; i += BLOCK) {
        start[lo + i] = e0 + lst[i];
        int d = deg[i];
        invdeg[lo + i] = 1.0f / (float)(d < 1 ? 1 : d);
    }

    if (ne <= CAP) {
        for (int i = e0 + tid; i < e1; i += BLOCK) {
            unsigned pr = pairs[i];
            int dl = pr >> 20;
            int sl = lst[dl] + atomicAdd(&cur[dl], 1);
            scsr[sl] = (int)(pr & 0xFFFFFu);
        }
        __syncthreads();
        for (int i = tid; i < ne; i += BLOCK) csr_src[e0 + i] = scsr[i];
    } else {
        for (int i = e0 + tid; i < e1; i += BLOCK) {
            unsigned pr = pairs[i];
            int dl = pr >> 20;
            int sl = lst[dl] + atomicAdd(&cur[dl], 1);
            csr_src[e0 + sl] = (int)(pr & 0xFFFFFu);
        }
    }
}

// ---------------- fused gather (D=32, relu) + next-layer MFMA projection ----------------
// Block = 16 nodes. Phase A: feature-parallel gather -> LDS h tile [16][32]
// bf16. Phase B: wave t does one 16x16x32 MFMA (A from LDS, B = Wt row-frags).
template<int DNEXT>
__global__ __launch_bounds__(256, 8)
void gather_proj(const unsigned short* __restrict__ p,
                 const int* __restrict__ csr_src,
                 const int* __restrict__ start,
                 const unsigned short* __restrict__ pre,
                 const float* __restrict__ invdeg,
                 const unsigned short* __restrict__ Wt,   // [2*DNEXT][32] bf16
                 const float* __restrict__ bias,          // [DNEXT]
                 unsigned short* __restrict__ pre_out,    // [N][DNEXT] bf16
                 unsigned short* __restrict__ p_out,      // [N][DNEXT] bf16
                 int n_nodes) {
    constexpr int NTILE = 2 * DNEXT / 16;   // 4 (DNEXT=32) or 2 (DNEXT=16)
    __shared__ unsigned short sh[16][32];

    int tid = threadIdx.x;
    int wv = tid >> 6, lane = tid & 63;
    int base = blockIdx.x * 16;
    int f = lane & 31;

    // ---- phase A: gather 4 nodes per wave (2 per iteration) ----
#pragma unroll
    for (int it = 0; it < 2; ++it) {
        int nl = wv * 4 + it * 2 + (lane >> 5);
        int g = base + nl;
        float v = 0.f;
        if (g < n_nodes) {
            int s0 = start[g];
            int s1 = start[g + 1];
            float a0 = 0.f, a1 = 0.f, a2 = 0.f, a3 = 0.f;
            float a4 = 0.f, a5 = 0.f, a6 = 0.f, a7 = 0.f;
            int j = s0;
            for (; j + 16 <= s1; j += 16) {
                int c[16];
#pragma unroll
                for (int q = 0; q < 16; ++q) c[q] = csr_src[j + q];
                unsigned short u[16];
#pragma unroll
                for (int q = 0; q < 16; ++q) u[q] = p[(size_t)c[q] * 32 + f];
                a0 += bf2f(u[0]) + bf2f(u[8]);
                a1 += bf2f(u[1]) + bf2f(u[9]);
                a2 += bf2f(u[2]) + bf2f(u[10]);
                a3 += bf2f(u[3]) + bf2f(u[11]);
                a4 += bf2f(u[4]) + bf2f(u[12]);
                a5 += bf2f(u[5]) + bf2f(u[13]);
                a6 += bf2f(u[6]) + bf2f(u[14]);
                a7 += bf2f(u[7]) + bf2f(u[15]);
            }
            for (; j + 4 <= s1; j += 4) {
                int c0 = csr_src[j], c1 = csr_src[j + 1];
                int c2 = csr_src[j + 2], c3 = csr_src[j + 3];
                a0 += bf2f(p[(size_t)c0 * 32 + f]);
                a1 += bf2f(p[(size_t)c1 * 32 + f]);
                a2 += bf2f(p[(size_t)c2 * 32 + f]);
                a3 += bf2f(p[(size_t)c3 * 32 + f]);
            }
            for (; j < s1; ++j)
                a4 += bf2f(p[(size_t)csr_src[j] * 32 + f]);
            float a = ((a0 + a1) + (a2 + a3)) + ((a4 + a5) + (a6 + a7));
            size_t o = (size_t)g * 32 + f;
            v = bf2f(pre[o]) + a * invdeg[g];
            v = fmaxf(v, 0.f);   // relu (layers 1,2 always relu)
        }
        sh[nl][f] = bf16r(v);
    }
    __syncthreads();

    // ---- phase B: wave wv computes tile t=wv of the next projection ----
    int t = wv;
    if (t >= NTILE) return;
    int col = lane & 15, kg = lane >> 4;

    bf16x8 A = *reinterpret_cast<const bf16x8*>(&sh[col][kg * 8]);
    bf16x8 B = *reinterpret_cast<const bf16x8*>(
        Wt + (size_t)(t * 16 + col) * 32 + kg * 8);
    f32x4 acc = (f32x4){0.f, 0.f, 0.f, 0.f};
    acc = __builtin_amdgcn_mfma_f32_16x16x32_bf16(A, B, acc, 0, 0, 0);

    int out = t * 16 + col;
    int nodeb = base + kg * 4;
#pragma unroll
    for (int r = 0; r < 4; ++r) {
        int node = nodeb + r;
        if (node >= n_nodes) continue;
        if (out < DNEXT) {
            pre_out[(size_t)node * DNEXT + out] = bf16r(acc[r] + bias[out]);
        } else {
            p_out[(size_t)node * DNEXT + (out - DNEXT)] = bf16r(acc[r]);
        }
    }
}

// ---------------- final feature-parallel bf16 gather (D=16, fp32 out) ----------------
__global__ void gather_final(const unsigned short* __restrict__ p,
                             const int* __restrict__ csr_src,
                             const int* __restrict__ start,
                             const unsigned short* __restrict__ pre,
                             const float* __restrict__ invdeg,
                             float* __restrict__ out,
                             int n_nodes) {
    constexpr int D = 16;
    constexpr int NPW = 64 / D;   // 4
    int wave = threadIdx.x >> 6;
    int lane = threadIdx.x & 63;
    int g = (blockIdx.x * (blockDim.x >> 6) + wave) * NPW + lane / D;
    int f = lane % D;
    if (g >= n_nodes) return;
    int s0 = start[g];
    int s1 = start[g + 1];
    float a0 = 0.f, a1 = 0.f, a2 = 0.f, a3 = 0.f;
    float a4 = 0.f, a5 = 0.f, a6 = 0.f, a7 = 0.f;
    int j = s0;
    for (; j + 16 <= s1; j += 16) {
        int c[16];
#pragma unroll
        for (int q = 0; q < 16; ++q) c[q] = csr_src[j + q];
        unsigned short u[16];
#pragma unroll
        for (int q = 0; q < 16; ++q) u[q] = p[(size_t)c[q] * D + f];
        a0 += bf2f(u[0]) + bf2f(u[8]);
        a1 += bf2f(u[1]) + bf2f(u[9]);
        a2 += bf2f(u[2]) + bf2f(u[10]);
        a3 += bf2f(u[3]) + bf2f(u[11]);
        a4 += bf2f(u[4]) + bf2f(u[12]);
        a5 += bf2f(u[5]) + bf2f(u[13]);
        a6 += bf2f(u[6]) + bf2f(u[14]);
        a7 += bf2f(u[7]) + bf2f(u[15]);
    }
    for (; j + 4 <= s1; j += 4) {
        int c0 = csr_src[j], c1 = csr_src[j + 1];
        int c2 = csr_src[j + 2], c3 = csr_src[j + 3];
        a0 += bf2f(p[(size_t)c0 * D + f]);
        a1 += bf2f(p[(size_t)c1 * D + f]);
        a2 += bf2f(p[(size_t)c2 * D + f]);
        a3 += bf2f(p[(size_t)c3 * D + f]);
    }
    for (; j < s1; ++j)
        a4 += bf2f(p[(size_t)csr_src[j] * D + f]);
    float a = ((a0 + a1) + (a2 + a3)) + ((a4 + a5) + (a6 + a7));
    size_t o = (size_t)g * D + f;
    out[o] = bf2f(pre[o]) + a * invdeg[g];
}

extern "C" void kernel_launch(void* const* d_in, const int* in_sizes, int n_in,
                              void* d_out, int out_size, void* d_ws, size_t ws_size,
                              hipStream_t stream) {
    const float* x        = (const float*)d_in[0];
    const int*   edge_src = (const int*)d_in[1];
    const int*   edge_dst = (const int*)d_in[2];
    const float* Ws1 = (const float*)d_in[3];
    const float* Wn1 = (const float*)d_in[4];
    const float* b1  = (const float*)d_in[5];
    const float* Ws2 = (const float*)d_in[6];
    const float* Wn2 = (const float*)d_in[7];
    const float* b2  = (const float*)d_in[8];
    const float* Ws3 = (const float*)d_in[9];
    const float* Wn3 = (const float*)d_in[10];
    const float* b3  = (const float*)d_in[11];
    float* out = (float*)d_out;

    const int IN = 128, HID = 32;
    const int n_nodes = in_sizes[0] / IN;
    const int n_edges = in_sizes[1];
    const int nbuk = (n_nodes + (1 << BSH) - 1) >> BSH;   // 196
    const int ch   = (n_edges + NBLK - 1) / NBLK;         // 6250

    char* wsb = (char*)d_ws;
    size_t off = 0;
    auto alloc = [&](size_t bytes) { char* r = wsb + off; off = (off + bytes + 255) & ~(size_t)255; return r; };
    int*   startp = (int*)alloc(((size_t)n_nodes + 1) * sizeof(int));
    float* invdeg = (float*)alloc((size_t)n_nodes * sizeof(float));
    int*   csr    = (int*)alloc((size_t)n_edges * sizeof(int));
    int*   hist   = (int*)alloc((size_t)nbuk * NBLK * sizeof(int));
    int*   buktot = (int*)alloc(256 * sizeof(int));
    int*   bukoff = (int*)alloc(257 * sizeof(int));
    unsigned short* Wt1 = (unsigned short*)alloc(64 * 128 * 2);
    unsigned short* Wt2 = (unsigned short*)alloc(64 * 32 * 2);
    unsigned short* Wt3 = (unsigned short*)alloc(32 * 32 * 2);
    unsigned* pairs = (unsigned*)alloc((size_t)n_edges * sizeof(unsigned));
    unsigned short* B0 = (unsigned short*)alloc((size_t)n_nodes * HID * 2);  // pre1 / pre3
    unsigned short* B1 = (unsigned short*)alloc((size_t)n_nodes * HID * 2);  // p1 / p3
    unsigned short* C0 = (unsigned short*)alloc((size_t)n_nodes * HID * 2);  // pre2
    unsigned short* C1 = (unsigned short*)alloc((size_t)n_nodes * HID * 2);  // p2

    const int gP   = (n_nodes + 63) / 64;       // proj1: 64 nodes/block
    const int gGP  = (n_nodes + 15) / 16;       // fused gather+proj: 16 nodes/block
    const int gGat16 = (n_nodes + 15) / 16;     // final gather: 16 nodes/block

    // ---- prep, then stage1 = hist (256 blocks) || proj1 (gP blocks) ----
    prep_kernel  <<<64, BLOCK, 0, stream>>>(Ws1, Wn1, Ws2, Wn2, Ws3, Wn3, Wt1, Wt2, Wt3);
    stage1_kernel<<<NBLK + gP, BLOCK, 0, stream>>>(edge_dst, hist, n_edges, nbuk, ch,
                                                   x, Wt1, b1, B0, B1, n_nodes, NBLK);
    scanBlk_kernel<<<nbuk, BLOCK, 0, stream>>>(hist, buktot);
    scanBuk_kernel<<<1, BLOCK, 0, stream>>>(buktot, bukoff, nbuk, startp, n_nodes, n_edges);
    part_kernel   <<<NBLK, BLOCK, 0, stream>>>(edge_src, edge_dst, hist, bukoff, pairs, n_edges, nbuk, ch);
    build_kernel  <<<nbuk, BLOCK, 0, stream>>>(pairs, bukoff, startp, invdeg, csr, n_nodes);

    // ---- gather1 + proj2 fused: reads pre1/p1 (B0/B1), writes pre2/p2 (C0/C1) ----
    gather_proj<32><<<gGP, BLOCK, 0, stream>>>(B1, csr, startp, B0, invdeg, Wt2, b2, C0, C1, n_nodes);

    // ---- gather2 + proj3 fused: reads pre2/p2 (C0/C1), writes pre3/p3 (B0/B1) ----
    gather_proj<16><<<gGP, BLOCK, 0, stream>>>(C1, csr, startp, C0, invdeg, Wt3, b3, B0, B1, n_nodes);

    // ---- final gather: out = pre3 + mean p3 (fp32 out) ----
    gather_final<<<gGat16, BLOCK, 0, stream>>>(B1, csr, startp, B0, invdeg, out, n_nodes);
}